// Round 3
// baseline (2457.116 us; speedup 1.0000x reference)
//
#include <hip/hip_runtime.h>

typedef unsigned short u16;
typedef unsigned int u32;
using short8 = __attribute__((ext_vector_type(8))) short;
using floatx4 = __attribute__((ext_vector_type(4))) float;

#define DMODEL 1024
#define DFF 4096
#define INNER 2048
#define DH 128
#define CTX 200
#define R_TOT 16000
#define ABN 40  // attention bn per chunk (2 chunks)
#define AROWS (ABN * CTX)
#define AM (ABN * 8)
#define SCALE_Q 0.08838834764831845f

__device__ __forceinline__ u16 f2bf(float f) {
    union { float f; u32 u; } v; v.f = f;
    u32 r = v.u + 0x7FFFu + ((v.u >> 16) & 1u);
    return (u16)(r >> 16);
}
__device__ __forceinline__ float bf2f(u16 u) {
    union { u32 u; float f; } v; v.u = ((u32)u) << 16; return v.f;
}
__device__ __forceinline__ float sigmoidf_(float x) { return 1.f / (1.f + __expf(-x)); }

// ---------------- GEMM core: 128x128 tile, BK=64, 4 waves, 2-phase dbuf pipeline ----------
__device__ __forceinline__ void load_lds16(const void* g, void* l) {
    __builtin_amdgcn_global_load_lds((const __attribute__((address_space(1))) u32*)g,
                                     (__attribute__((address_space(3))) u32*)l, 16, 0, 0);
}

// Stage [128 rows][64 k] bf16 tile into LDS; XOR swizzle ((row&7)<<4) pre-applied on the
// per-lane GLOBAL source address (global_load_lds dst is linear: base + lane*16).
// 4 global_load_lds per wave per call.
template <typename RowMap>
__device__ __forceinline__ void stage_tile_g(const char* __restrict__ src, RowMap rowoff,
                                             int nrows, int row0, int k0b, char* tile) {
    const int lane = threadIdx.x & 63;
    const int wave = threadIdx.x >> 6;
#pragma unroll
    for (int r = 0; r < 4; ++r) {
        int o = r * 4096 + wave * 1024 + lane * 16;
        int row = o >> 7;
        int srcb = (o & 127) ^ ((row & 7) << 4);
        int grow = row0 + row;
        grow = (grow < nrows) ? grow : (nrows - 1);
        const char* g = src + rowoff(grow) + k0b + srcb;
        load_lds16(g, tile + r * 4096 + wave * 1024);
    }
}

// lds must be 2*32768 bytes. Pipeline per K-step:
//   { issue next-tile stage (8 loads/wave) ; vmcnt(8) ; s_barrier ; ds_read+MFMA ;
//     lgkmcnt(0) ; s_barrier }
// Counted vmcnt keeps the next tile's loads in flight across the compute phase.
template <typename RMA, typename RMB, typename Epi>
__device__ __forceinline__ void gemm_core_g(const char* __restrict__ A, RMA rma, int a_rows,
                                            const char* __restrict__ B, RMB rmb, int b_rows,
                                            int K, int row0, int col0, char* lds, Epi epi) {
    const int lane = threadIdx.x & 63;
    const int wave = threadIdx.x >> 6;
    const int wrow = (wave >> 1) * 64;
    const int wcol = (wave & 1) * 64;
    const int lr = lane & 15;
    const int kg = lane >> 4;
    const int nt = K >> 6;

    floatx4 acc[4][4];
#pragma unroll
    for (int i = 0; i < 4; ++i)
#pragma unroll
        for (int j = 0; j < 4; ++j) acc[i][j] = (floatx4){0.f, 0.f, 0.f, 0.f};

    // prologue: stage tile 0 into buf0
    stage_tile_g(A, rma, a_rows, row0, 0, lds);
    stage_tile_g(B, rmb, b_rows, col0, 0, lds + 16384);

    for (int t = 0; t < nt; ++t) {
        char* cur = lds + (t & 1) * 32768;
        if (t + 1 < nt) {
            char* nxt = lds + ((t + 1) & 1) * 32768;
            stage_tile_g(A, rma, a_rows, row0, (t + 1) << 7, nxt);
            stage_tile_g(B, rmb, b_rows, col0, (t + 1) << 7, nxt + 16384);
            asm volatile("s_waitcnt vmcnt(8)" ::: "memory");  // current tile landed
        } else {
            asm volatile("s_waitcnt vmcnt(0)" ::: "memory");
        }
        __builtin_amdgcn_s_barrier();
#pragma unroll
        for (int ks = 0; ks < 2; ++ks) {
            short8 av[4], bv[4];
#pragma unroll
            for (int mi = 0; mi < 4; ++mi) {
                int row = wrow + mi * 16 + lr;
                int cb = (ks * 64 + kg * 16) ^ ((row & 7) << 4);
                av[mi] = *(const short8*)(cur + row * 128 + cb);
            }
#pragma unroll
            for (int ni = 0; ni < 4; ++ni) {
                int row = wcol + ni * 16 + lr;
                int cb = (ks * 64 + kg * 16) ^ ((row & 7) << 4);
                bv[ni] = *(const short8*)(cur + 16384 + row * 128 + cb);
            }
#pragma unroll
            for (int mi = 0; mi < 4; ++mi)
#pragma unroll
                for (int ni = 0; ni < 4; ++ni)
                    acc[mi][ni] = __builtin_amdgcn_mfma_f32_16x16x32_bf16(av[mi], bv[ni],
                                                                          acc[mi][ni], 0, 0, 0);
        }
        asm volatile("s_waitcnt lgkmcnt(0)" ::: "memory");  // reads of cur done before reuse
        __builtin_amdgcn_s_barrier();
    }
#pragma unroll
    for (int mi = 0; mi < 4; ++mi)
#pragma unroll
        for (int ni = 0; ni < 4; ++ni)
#pragma unroll
            for (int rr = 0; rr < 4; ++rr)
                epi(row0 + wrow + mi * 16 + kg * 4 + rr, col0 + wcol + ni * 16 + lr,
                    acc[mi][ni][rr]);
}

// bijective XCD-chunked remap (m204): consecutive dispatch ids round-robin XCDs; give each
// XCD a contiguous range of linearized (col-major-panel) tile ids for L2 locality.
__device__ __forceinline__ void xcd_remap(int& bx, int& by) {
    const int gx = gridDim.x, nwg = gx * gridDim.y;
    const int orig = blockIdx.y * gx + blockIdx.x;
    const int q = nwg >> 3, r = nwg & 7, xcd = orig & 7;
    const int base = (xcd < r) ? xcd * (q + 1) : r * (q + 1) + (xcd - r) * q;
    const int wgid = base + (orig >> 3);
    bx = wgid % gx;
    by = wgid / gx;
}

// MODE 0: bf16 out = alpha*v + bias ; MODE 1: bf16 out = silu(v+bias) ;
// MODE 2: f32 out = alpha*(v+bias) + resid ; MODE 3: f32 out += alpha*v
template <int MODE>
__global__ __launch_bounds__(256, 2) void k_gemm(const u16* __restrict__ A, int lda,
                                                 const u16* __restrict__ Bt, int ldb,
                                                 const float* __restrict__ bias, float alpha,
                                                 void* out, int ldc, const float* resid, int M,
                                                 int N, int K) {
    __shared__ __align__(128) char lds[65536];
    int bx, by;
    xcd_remap(bx, by);
    const int row0 = bx * 128, col0 = by * 128;
    u16* ob = (u16*)out;
    float* of = (float*)out;
    const size_t la = (size_t)lda * 2, lb = (size_t)ldb * 2;
    gemm_core_g((const char*)A, [=](int r) { return (size_t)r * la; }, M,
                (const char*)Bt, [=](int r) { return (size_t)r * lb; }, N, K, row0, col0, lds,
                [&](int r, int c, float v) {
                    if (r >= M) return;
                    size_t idx = (size_t)r * ldc + c;
                    float bb = bias ? bias[c] : 0.f;
                    if (MODE == 0) {
                        ob[idx] = f2bf(alpha * v + bb);
                    } else if (MODE == 1) {
                        float t = v + bb;
                        ob[idx] = f2bf(t * sigmoidf_(t));
                    } else if (MODE == 2) {
                        of[idx] = alpha * (v + bb) + resid[idx];
                    } else {
                        of[idx] += alpha * v;
                    }
                });
}

// scores[z][i][j] = q_scaled[i].k[j]  (bf16, cols padded to 256), z = local bnh
__global__ __launch_bounds__(256, 2) void k_qk(const u16* __restrict__ q,
                                               const u16* __restrict__ kvc,
                                               u16* __restrict__ sc, int bn0) {
    __shared__ __align__(128) char lds[65536];
    const int z = blockIdx.z, bnl = z >> 3, h = z & 7;
    const char* A = (const char*)(q + ((size_t)(bn0 + bnl) * CTX) * DMODEL + h * DH);
    const char* B = (const char*)(kvc + ((size_t)bnl * CTX) * (2 * DMODEL) + h * DH);
    u16* out = sc + (size_t)z * CTX * 256;
    gemm_core_g(A, [](int r) { return (size_t)r * (DMODEL * 2); }, CTX, B,
                [](int r) { return (size_t)r * (4 * DMODEL); }, CTX, DH, blockIdx.x * 128,
                blockIdx.y * 128, lds, [&](int r, int c, float v) {
                    if (r < CTX) out[(size_t)r * 256 + c] = f2bf(v);
                });
}

// scores[m][i][j] += q'[m].rel[i][j]  (batched over i; A gathered from q via row map)
__global__ __launch_bounds__(256, 2) void k_pos(const u16* __restrict__ q,
                                                const u16* __restrict__ rel,
                                                u16* __restrict__ sc, int m0) {
    __shared__ __align__(128) char lds[65536];
    const int i = blockIdx.z;
    const char* B = (const char*)(rel + (size_t)i * CTX * DH);
    u16* out = sc + i * 256;
    gemm_core_g((const char*)q,
                [=](int r) {
                    int m = m0 + r;
                    return (size_t)(((m >> 3) * CTX + i) * DMODEL + (m & 7) * DH) * 2;
                },
                AM, B, [](int r) { return (size_t)r * (DH * 2); }, CTX, DH, blockIdx.x * 128,
                blockIdx.y * 128, lds, [&](int r, int c, float v) {
                    if (r < AM) {
                        size_t idx = (size_t)r * (CTX * 256) + c;
                        out[idx] = f2bf(bf2f(out[idx]) + v);
                    }
                });
}

// attn_out[(bn0+z/8)*CTX+i][(z&7)*DH+dh] = P[z][i][:].vT[z][dh][:]  (K=256 padded)
__global__ __launch_bounds__(256, 2) void k_pv(const u16* __restrict__ P,
                                               const u16* __restrict__ vT,
                                               u16* __restrict__ attn, int bn0) {
    __shared__ __align__(128) char lds[65536];
    const int z = blockIdx.z;
    u16* out = attn + ((size_t)(bn0 + (z >> 3)) * CTX) * DMODEL + (z & 7) * DH;
    const char* A = (const char*)(P + (size_t)z * CTX * 256);
    const char* B = (const char*)(vT + (size_t)z * DH * 256);
    gemm_core_g(A, [](int r) { return (size_t)r * 512; }, CTX, B,
                [](int r) { return (size_t)r * 512; }, DH, 256, blockIdx.x * 128, 0, lds,
                [&](int r, int c, float v) {
                    if (r < CTX) out[(size_t)r * DMODEL + c] = f2bf(v);
                });
}

// ---------------- LayerNorm ----------------
template <bool OUTF32>
__global__ __launch_bounds__(256) void k_ln(const float* __restrict__ x,
                                            const float* __restrict__ g,
                                            const float* __restrict__ b, void* __restrict__ out) {
    const int row = blockIdx.x, t = threadIdx.x, lane = t & 63, wv = t >> 6;
    const float4 v = ((const float4*)(x + (size_t)row * DMODEL))[t];
    float s = v.x + v.y + v.z + v.w;
    float q = v.x * v.x + v.y * v.y + v.z * v.z + v.w * v.w;
#pragma unroll
    for (int off = 32; off > 0; off >>= 1) { s += __shfl_down(s, off); q += __shfl_down(q, off); }
    __shared__ float rs_[4], rq_[4];
    if (lane == 0) { rs_[wv] = s; rq_[wv] = q; }
    __syncthreads();
    s = rs_[0] + rs_[1] + rs_[2] + rs_[3];
    q = rq_[0] + rq_[1] + rq_[2] + rq_[3];
    const float mu = s * (1.f / DMODEL);
    const float rstd = rsqrtf(q * (1.f / DMODEL) - mu * mu + 1e-5f);
    const float4 gv = ((const float4*)g)[t];
    const float4 bv = ((const float4*)b)[t];
    float o0 = (v.x - mu) * rstd * gv.x + bv.x;
    float o1 = (v.y - mu) * rstd * gv.y + bv.y;
    float o2 = (v.z - mu) * rstd * gv.z + bv.z;
    float o3 = (v.w - mu) * rstd * gv.w + bv.w;
    if (OUTF32) {
        ((float4*)out)[(size_t)row * 256 + t] = make_float4(o0, o1, o2, o3);
    } else {
        ushort4 r4;
        r4.x = f2bf(o0); r4.y = f2bf(o1); r4.z = f2bf(o2); r4.w = f2bf(o3);
        ((ushort4*)out)[(size_t)row * 256 + t] = r4;
    }
}

// softmax over j, in-place on bf16 scores; zeroes pad cols [CTX,256)
__global__ __launch_bounds__(256) void k_softmax(u16* __restrict__ sc) {
    const size_t row = blockIdx.x;
    const int t = threadIdx.x, lane = t & 63, wv = t >> 6;
    float v = (t < CTX) ? bf2f(sc[row * 256 + t]) : -3.0e38f;
    float m = v;
#pragma unroll
    for (int off = 32; off > 0; off >>= 1) m = fmaxf(m, __shfl_down(m, off));
    __shared__ float rm[4], rsum[4];
    if (lane == 0) rm[wv] = m;
    __syncthreads();
    m = fmaxf(fmaxf(rm[0], rm[1]), fmaxf(rm[2], rm[3]));
    float e = (t < CTX) ? __expf(v - m) : 0.f;
    float s = e;
#pragma unroll
    for (int off = 32; off > 0; off >>= 1) s += __shfl_down(s, off);
    if (lane == 0) rsum[wv] = s;
    __syncthreads();
    s = rsum[0] + rsum[1] + rsum[2] + rsum[3];
    sc[row * 256 + t] = f2bf(e / s);
}

// GLU: out = a * sigmoid(gate), flat [16000*1024], in-place on a
__global__ __launch_bounds__(256) void k_glu(u16* __restrict__ a, const u16* __restrict__ gate) {
    const size_t base = ((size_t)blockIdx.x * 256 + threadIdx.x) * 8;
    const short8 a8 = *(const short8*)(a + base);
    const short8 g8 = *(const short8*)(gate + base);
    short8 o8;
#pragma unroll
    for (int e = 0; e < 8; ++e) {
        float av = bf2f((u16)a8[e]), gg = bf2f((u16)g8[e]);
        o8[e] = (short)f2bf(av * sigmoidf_(gg));
    }
    *(short8*)(a + base) = o8;
}

// depthwise conv(K=15,pad=7)+BN(eval)+silu on [8][2000][1024] slice; c0 = channel offset
__global__ __launch_bounds__(256) void k_dwconv(const u16* __restrict__ glu,
                                                const float* __restrict__ w,
                                                const float* __restrict__ bng,
                                                const float* __restrict__ bnb,
                                                const float* __restrict__ bnm,
                                                const float* __restrict__ bnv,
                                                u16* __restrict__ out, int c0) {
    const int b = blockIdx.z, lt = blockIdx.x, cg = blockIdx.y;
    const int c = cg * 256 + threadIdx.x;
    const int gc = c0 + c;
    const int l0 = lt * 16;
    __shared__ u16 s[30][256];
#pragma unroll
    for (int rr = 0; rr < 30; ++rr) {
        int l = l0 + rr - 7;
        u16 v = 0;
        if (l >= 0 && l < 2000) v = glu[((size_t)b * 2000 + l) * 1024 + c];
        s[rr][threadIdx.x] = v;
    }
    __syncthreads();
    float wv[15];
#pragma unroll
    for (int k = 0; k < 15; ++k) wv[k] = w[gc * 15 + k];
    const float sc = rsqrtf(bnv[gc] + 1e-5f) * bng[gc];
    const float mean = bnm[gc], bb = bnb[gc];
#pragma unroll
    for (int l = 0; l < 16; ++l) {
        float acc = 0.f;
#pragma unroll
        for (int k = 0; k < 15; ++k) acc += bf2f(s[l + k][threadIdx.x]) * wv[k];
        float h = (acc - mean) * sc + bb;
        h = h * sigmoidf_(h);
        out[((size_t)b * 2000 + l0 + l) * 1024 + c] = f2bf(h);
    }
}

// weight transpose f32[K,N] -> bf16[N,K]
__global__ __launch_bounds__(256) void k_wt(const float* __restrict__ w, u16* __restrict__ wt,
                                            int K, int N) {
    __shared__ float tile[32][33];
    const int k0 = blockIdx.x * 32, n0 = blockIdx.y * 32;
    const int tx = threadIdx.x & 31, ty = threadIdx.x >> 5;
#pragma unroll
    for (int i = 0; i < 32; i += 8) tile[ty + i][tx] = w[(size_t)(k0 + ty + i) * N + n0 + tx];
    __syncthreads();
#pragma unroll
    for (int i = 0; i < 32; i += 8)
        wt[(size_t)(n0 + ty + i) * K + k0 + tx] = f2bf(tile[tx][ty + i]);
}

// rel_bf16[i][j][dh] = bf16(rel_emb[dist[i][j]][dh])
__global__ void k_rel(const float* __restrict__ emb, const int* __restrict__ dist,
                      u16* __restrict__ rel) {
    const int bid = blockIdx.x;
    const int d = dist[bid];
    rel[(size_t)bid * DH + threadIdx.x] = f2bf(emb[(size_t)d * DH + threadIdx.x]);
}

// vT[z][dh][j] = v_chunk[bnl*CTX+j][DMODEL + h*DH + dh], zero-padded j in [CTX,256)
__global__ __launch_bounds__(256) void k_vt(const u16* __restrict__ kvc, u16* __restrict__ vT) {
    __shared__ u16 t_[64 * 130];
    const int z = blockIdx.x, jt = blockIdx.y;
    const int bnl = z >> 3, h = z & 7;
    const int j0 = jt * 64;
    for (int idx = threadIdx.x; idx < 8192; idx += 256) {
        int j = idx >> 7, dh = idx & 127;
        int jj = j0 + j;
        u16 val = 0;
        if (jj < CTX) val = kvc[((size_t)(bnl * CTX + jj)) * (2 * DMODEL) + DMODEL + h * DH + dh];
        t_[j * 130 + dh] = val;
    }
    __syncthreads();
    for (int idx = threadIdx.x; idx < 8192; idx += 256) {
        int dh = idx >> 6, j = idx & 63;
        vT[((size_t)z * DH + dh) * 256 + j0 + j] = t_[j * 130 + dh];
    }
}

__global__ void k_fill(float* o, int n, float v) {
    int i = blockIdx.x * 256 + threadIdx.x;
    if (i < n) o[i] = v;
}

extern "C" void kernel_launch(void* const* d_in, const int* in_sizes, int n_in, void* d_out,
                              int out_size, void* d_ws, size_t ws_size, hipStream_t stream) {
    const float* x_in = (const float*)d_in[0];
    const int* dists = (const int*)d_in[1];
    const float* ff1_ln_g = (const float*)d_in[2];
    const float* ff1_ln_b = (const float*)d_in[3];
    const float* ff1_up_w = (const float*)d_in[4];
    const float* ff1_up_b = (const float*)d_in[5];
    const float* ff1_down_w = (const float*)d_in[6];
    const float* ff1_down_b = (const float*)d_in[7];
    const float* attn_ln_g = (const float*)d_in[8];
    const float* attn_ln_b = (const float*)d_in[9];
    const float* wq = (const float*)d_in[10];
    const float* wkv = (const float*)d_in[11];
    const float* wo = (const float*)d_in[12];
    const float* wo_b = (const float*)d_in[13];
    const float* rel_emb = (const float*)d_in[14];
    const float* conv_ln_g = (const float*)d_in[15];
    const float* conv_ln_b = (const float*)d_in[16];
    const float* conv_up_w = (const float*)d_in[17];
    const float* conv_up_b = (const float*)d_in[18];
    const float* dw_w = (const float*)d_in[19];
    const float* bn_g = (const float*)d_in[20];
    const float* bn_b = (const float*)d_in[21];
    const float* bn_mean = (const float*)d_in[22];
    const float* bn_var = (const float*)d_in[23];
    const float* conv_down_w = (const float*)d_in[24];
    const float* conv_down_b = (const float*)d_in[25];
    const float* ff2_ln_g = (const float*)d_in[26];
    const float* ff2_ln_b = (const float*)d_in[27];
    const float* ff2_up_w = (const float*)d_in[28];
    const float* ff2_up_b = (const float*)d_in[29];
    const float* ff2_down_w = (const float*)d_in[30];
    const float* ff2_down_b = (const float*)d_in[31];
    const float* post_ln_g = (const float*)d_in[32];
    const float* post_ln_b = (const float*)d_in[33];

    char* W = (char*)d_ws;
    size_t off = 0;
    auto alloc = [&](size_t bytes) {
        char* p = W + off;
        off += (bytes + 255) & ~(size_t)255;
        return (u16*)p;
    };
    u16* slotA = alloc((size_t)4096 * 1024 * 2);        // up / q / kv / wo weights
    u16* slotB = alloc((size_t)4096 * 1024 * 2);        // down weights
    u16* rel_bf = alloc((size_t)CTX * CTX * DH * 2);    // 10.2 MB
    u16* ln_buf = alloc((size_t)R_TOT * DMODEL * 2);    // 32.8 MB
    u16* bufA = alloc((size_t)AROWS * 2 * DMODEL * 2);  // 32.8 MB  kv / gate / conv-out
    u16* bufB = alloc((size_t)R_TOT * DMODEL * 2);      // 32.8 MB  q / attn_out
    u16* smid = alloc((size_t)R_TOT * DMODEL * 2);      // 32.8 MB  FF-mid-slice / scores / glu-a
    u16* vT = alloc((size_t)AM * DH * 256 * 2);         // 21.0 MB
    float* xs = (float*)d_out;                          // f32 residual stream in d_out

    if (ws_size < off) {  // sentinel: absmax ~= 31337 means ws too small
        k_fill<<<(out_size + 255) / 256, 256, 0, stream>>>((float*)d_out, out_size, 31337.f);
        return;
    }

    auto WT = [&](const float* s, u16* d, int K, int N) {
        k_wt<<<dim3(K / 32, N / 32), 256, 0, stream>>>(s, d, K, N);
    };

    k_rel<<<CTX * CTX, 128, 0, stream>>>(rel_emb, dists, rel_bf);

    // ---- FF helper: x = 0.5*(silu(ln@Wup+bu)@Wdn + bd) + resid, K-split into 4 slices ----
    auto ff_block = [&](const float* lng, const float* lnb, const float* upb,
                        const float* dnb, const float* resid0, const float* xsrc) {
        k_ln<false><<<R_TOT, 256, 0, stream>>>(xsrc, lng, lnb, ln_buf);
        for (int kc = 0; kc < 4; ++kc) {
            k_gemm<1><<<dim3(125, 8), 256, 0, stream>>>(
                ln_buf, DMODEL, slotA + (size_t)kc * 1024 * 1024, DMODEL, upb + kc * 1024, 1.f,
                smid, DMODEL, nullptr, R_TOT, DMODEL, DMODEL);
            if (kc == 0)
                k_gemm<2><<<dim3(125, 8), 256, 0, stream>>>(smid, DMODEL, slotB + kc * 1024, DFF,
                                                            dnb, 0.5f, xs, DMODEL, resid0, R_TOT,
                                                            DMODEL, DMODEL);
            else
                k_gemm<3><<<dim3(125, 8), 256, 0, stream>>>(smid, DMODEL, slotB + kc * 1024, DFF,
                                                            nullptr, 0.5f, xs, DMODEL, nullptr,
                                                            R_TOT, DMODEL, DMODEL);
        }
    };

    // ---- FF1 ----
    WT(ff1_up_w, slotA, 1024, 4096);
    WT(ff1_down_w, slotB, 4096, 1024);
    ff_block(ff1_ln_g, ff1_ln_b, ff1_up_b, ff1_down_b, x_in, x_in);

    // ---- Attention ----
    k_ln<false><<<R_TOT, 256, 0, stream>>>(xs, attn_ln_g, attn_ln_b, ln_buf);
    WT(wq, slotA, 1024, 1024);
    k_gemm<0><<<dim3(125, 8), 256, 0, stream>>>(ln_buf, DMODEL, slotA, DMODEL, nullptr, SCALE_Q,
                                                bufB, DMODEL, nullptr, R_TOT, DMODEL, DMODEL);
    WT(wkv, slotA, 1024, 2048);
    for (int h = 0; h < 2; ++h) {
        const int bn0 = h * ABN, m0 = bn0 * 8;
        const u16* lnc = ln_buf + (size_t)bn0 * CTX * DMODEL;
        k_gemm<0><<<dim3(63, 16), 256, 0, stream>>>(lnc, DMODEL, slotA, DMODEL, nullptr, 1.f,
                                                    bufA, 2 * DMODEL, nullptr, AROWS, 2 * DMODEL,
                                                    DMODEL);
        k_vt<<<dim3(AM, 4), 256, 0, stream>>>(bufA, vT);
        k_qk<<<dim3(2, 2, AM), 256, 0, stream>>>(bufB, bufA, smid, bn0);
        k_pos<<<dim3(3, 2, CTX), 256, 0, stream>>>(bufB, rel_bf, smid, m0);
        k_softmax<<<AM * CTX, 256, 0, stream>>>(smid);
        k_pv<<<dim3(2, 1, AM), 256, 0, stream>>>(smid, vT, bufB, bn0);
    }
    WT(wo, slotA, 1024, 1024);
    k_gemm<2><<<dim3(125, 8), 256, 0, stream>>>(bufB, DMODEL, slotA, DMODEL, wo_b, 1.f, xs,
                                                DMODEL, xs, R_TOT, DMODEL, DMODEL);

    // ---- Conv module (2 channel-slices of 1024) ----
    k_ln<false><<<R_TOT, 256, 0, stream>>>(xs, conv_ln_g, conv_ln_b, ln_buf);
    WT(conv_up_w, slotA, 1024, 4096);
    WT(conv_down_w, slotB, 2048, 1024);
    for (int kc = 0; kc < 2; ++kc) {
        // a-part -> smid ; gate-part -> bufA
        k_gemm<0><<<dim3(125, 8), 256, 0, stream>>>(
            ln_buf, DMODEL, slotA + (size_t)kc * 1024 * 1024, DMODEL, conv_up_b + kc * 1024, 1.f,
            smid, DMODEL, nullptr, R_TOT, DMODEL, DMODEL);
        k_gemm<0><<<dim3(125, 8), 256, 0, stream>>>(
            ln_buf, DMODEL, slotA + (size_t)(2048 + kc * 1024) * 1024, DMODEL,
            conv_up_b + 2048 + kc * 1024, 1.f, bufA, DMODEL, nullptr, R_TOT, DMODEL, DMODEL);
        k_glu<<<R_TOT * DMODEL / 8 / 256, 256, 0, stream>>>(smid, bufA);
        k_dwconv<<<dim3(125, 4, 8), 256, 0, stream>>>(smid, dw_w, bn_g, bn_b, bn_mean, bn_var,
                                                      bufA, kc * 1024);
        if (kc == 0)
            k_gemm<2><<<dim3(125, 8), 256, 0, stream>>>(bufA, DMODEL, slotB + kc * 1024, INNER,
                                                        conv_down_b, 1.f, xs, DMODEL, xs, R_TOT,
                                                        DMODEL, DMODEL);
        else
            k_gemm<3><<<dim3(125, 8), 256, 0, stream>>>(bufA, DMODEL, slotB + kc * 1024, INNER,
                                                        nullptr, 1.f, xs, DMODEL, nullptr, R_TOT,
                                                        DMODEL, DMODEL);
    }

    // ---- FF2 ----
    WT(ff2_up_w, slotA, 1024, 4096);
    WT(ff2_down_w, slotB, 4096, 1024);
    ff_block(ff2_ln_g, ff2_ln_b, ff2_up_b, ff2_down_b, xs, xs);

    // ---- final LayerNorm (in-place on d_out) ----
    k_ln<true><<<R_TOT, 256, 0, stream>>>(xs, post_ln_g, post_ln_b, d_out);
}

// Round 4
// 2277.826 us; speedup vs baseline: 1.0787x; 1.0787x over previous
//
#include <hip/hip_runtime.h>

typedef unsigned short u16;
typedef unsigned int u32;
using short8 = __attribute__((ext_vector_type(8))) short;
using floatx4 = __attribute__((ext_vector_type(4))) float;

#define DMODEL 1024
#define DFF 4096
#define INNER 2048
#define DH 128
#define CTX 200
#define R_TOT 16000
#define ABN 40  // attention bn per chunk (2 chunks)
#define AROWS (ABN * CTX)
#define AM (ABN * 8)
#define SCALE_Q 0.08838834764831845f

__device__ __forceinline__ u16 f2bf(float f) {
    union { float f; u32 u; } v; v.f = f;
    u32 r = v.u + 0x7FFFu + ((v.u >> 16) & 1u);
    return (u16)(r >> 16);
}
__device__ __forceinline__ float bf2f(u16 u) {
    union { u32 u; float f; } v; v.u = ((u32)u) << 16; return v.f;
}
__device__ __forceinline__ float sigmoidf_(float x) { return 1.f / (1.f + __expf(-x)); }

__device__ __forceinline__ void load_lds16(const void* g, void* l) {
    __builtin_amdgcn_global_load_lds((const __attribute__((address_space(1))) u32*)g,
                                     (__attribute__((address_space(3))) u32*)l, 16, 0, 0);
}

// ============== 256x256 tile GEMM: BK=64, 8 waves (2Mx4N), 2-phase dbuf ==============
// Stage [256 rows][64 k] bf16 (32 KB) with XOR swizzle ((row&7)<<4) pre-applied on the
// per-lane GLOBAL source address; LDS dst is linear. 4 loads/thread (512 threads).
template <typename RowMap>
__device__ __forceinline__ void stage256(const char* __restrict__ src, RowMap rowoff, int nrows,
                                         int row0, int k0b, char* dst) {
    const int lane = threadIdx.x & 63;
    const int wave = threadIdx.x >> 6;
#pragma unroll
    for (int r = 0; r < 4; ++r) {
        int o = r * 8192 + wave * 1024 + lane * 16;
        int row = o >> 7;
        int srcb = (o & 127) ^ ((row & 7) << 4);
        int grow = row0 + row;
        grow = (grow < nrows) ? grow : (nrows - 1);
        const char* g = src + rowoff(grow) + k0b + srcb;
        load_lds16(g, dst + r * 8192 + wave * 1024);
    }
}

// lds = 2 x {A:32KB, B:32KB} = 128 KB. Per K-tile: issue next-tile stage (8 loads) BEFORE
// compute; counted vmcnt(8) keeps them in flight across the MFMA phase (T3/T4 minimum).
template <typename RMA, typename RMB, typename Epi>
__device__ __forceinline__ void gemm256_core(const char* __restrict__ A, RMA rma, int a_rows,
                                             const char* __restrict__ B, RMB rmb, int b_rows,
                                             int K, int row0, int col0, char* lds, Epi epi) {
    const int lane = threadIdx.x & 63;
    const int wave = threadIdx.x >> 6;
    const int wrow = (wave >> 2) * 128;  // 2 wave-rows of 128
    const int wcol = (wave & 3) * 64;    // 4 wave-cols of 64
    const int lr = lane & 15;
    const int kg = lane >> 4;
    const int nt = K >> 6;

    floatx4 acc[8][4];
#pragma unroll
    for (int i = 0; i < 8; ++i)
#pragma unroll
        for (int j = 0; j < 4; ++j) acc[i][j] = (floatx4){0.f, 0.f, 0.f, 0.f};

    stage256(A, rma, a_rows, row0, 0, lds);
    stage256(B, rmb, b_rows, col0, 0, lds + 32768);

    for (int t = 0; t < nt; ++t) {
        char* cur = lds + (t & 1) * 65536;
        if (t + 1 < nt) {
            char* nxt = lds + ((t + 1) & 1) * 65536;
            stage256(A, rma, a_rows, row0, (t + 1) << 7, nxt);
            stage256(B, rmb, b_rows, col0, (t + 1) << 7, nxt + 32768);
            asm volatile("s_waitcnt vmcnt(8)" ::: "memory");  // tile t landed; t+1 in flight
        } else {
            asm volatile("s_waitcnt vmcnt(0)" ::: "memory");
        }
        __builtin_amdgcn_s_barrier();
#pragma unroll
        for (int ks = 0; ks < 2; ++ks) {
            short8 av[8], bv[4];
#pragma unroll
            for (int mi = 0; mi < 8; ++mi) {
                int row = wrow + mi * 16 + lr;
                int cb = (ks * 64 + kg * 16) ^ ((row & 7) << 4);
                av[mi] = *(const short8*)(cur + row * 128 + cb);
            }
#pragma unroll
            for (int ni = 0; ni < 4; ++ni) {
                int row = wcol + ni * 16 + lr;
                int cb = (ks * 64 + kg * 16) ^ ((row & 7) << 4);
                bv[ni] = *(const short8*)(cur + 32768 + row * 128 + cb);
            }
#pragma unroll
            for (int mi = 0; mi < 8; ++mi)
#pragma unroll
                for (int ni = 0; ni < 4; ++ni)
                    acc[mi][ni] = __builtin_amdgcn_mfma_f32_16x16x32_bf16(av[mi], bv[ni],
                                                                          acc[mi][ni], 0, 0, 0);
        }
        asm volatile("s_waitcnt lgkmcnt(0)" ::: "memory");  // cur reads done before reuse
        __builtin_amdgcn_s_barrier();
    }
#pragma unroll
    for (int mi = 0; mi < 8; ++mi)
#pragma unroll
        for (int ni = 0; ni < 4; ++ni)
#pragma unroll
            for (int rr = 0; rr < 4; ++rr)
                epi(row0 + wrow + mi * 16 + kg * 4 + rr, col0 + wcol + ni * 16 + lr,
                    acc[mi][ni][rr]);
}

// bijective XCD-chunked remap (m204)
__device__ __forceinline__ void xcd_remap(int& bx, int& by) {
    const int gx = gridDim.x, nwg = gx * gridDim.y;
    const int orig = blockIdx.y * gx + blockIdx.x;
    const int q = nwg >> 3, r = nwg & 7, xcd = orig & 7;
    const int base = (xcd < r) ? xcd * (q + 1) : r * (q + 1) + (xcd - r) * q;
    const int wgid = base + (orig >> 3);
    bx = wgid % gx;
    by = wgid / gx;
}

// MODE 0: bf16 out = alpha*v + bias ; MODE 1: bf16 out = silu(v+bias) ;
// MODE 2: f32 out = alpha*(v+bias) + resid ; MODE 3: f32 out += alpha*v
template <int MODE>
__global__ __launch_bounds__(512, 2) void k_gemm256(const u16* __restrict__ A, int lda,
                                                    const u16* __restrict__ Bt, int ldb,
                                                    const float* __restrict__ bias, float alpha,
                                                    void* out, int ldc, const float* resid,
                                                    int M, int N, int K) {
    __shared__ __align__(128) char lds[131072];
    int bx, by;
    xcd_remap(bx, by);
    const int row0 = bx * 256, col0 = by * 256;
    u16* ob = (u16*)out;
    float* of = (float*)out;
    const size_t la = (size_t)lda * 2, lb = (size_t)ldb * 2;
    gemm256_core((const char*)A, [=](int r) { return (size_t)r * la; }, M,
                 (const char*)Bt, [=](int r) { return (size_t)r * lb; }, N, K, row0, col0, lds,
                 [&](int r, int c, float v) {
                     if (r >= M) return;
                     size_t idx = (size_t)r * ldc + c;
                     float bb = bias ? bias[c] : 0.f;
                     if (MODE == 0) {
                         ob[idx] = f2bf(alpha * v + bb);
                     } else if (MODE == 1) {
                         float t = v + bb;
                         ob[idx] = f2bf(t * sigmoidf_(t));
                     } else if (MODE == 2) {
                         of[idx] = alpha * (v + bb) + resid[idx];
                     } else {
                         of[idx] += alpha * v;
                     }
                 });
}

// ============== 128x128 tile core (attention-internal GEMMs, proven) ==============
template <typename RowMap>
__device__ __forceinline__ void stage_tile_g(const char* __restrict__ src, RowMap rowoff,
                                             int nrows, int row0, int k0b, char* tile) {
    const int lane = threadIdx.x & 63;
    const int wave = threadIdx.x >> 6;
#pragma unroll
    for (int r = 0; r < 4; ++r) {
        int o = r * 4096 + wave * 1024 + lane * 16;
        int row = o >> 7;
        int srcb = (o & 127) ^ ((row & 7) << 4);
        int grow = row0 + row;
        grow = (grow < nrows) ? grow : (nrows - 1);
        const char* g = src + rowoff(grow) + k0b + srcb;
        load_lds16(g, tile + r * 4096 + wave * 1024);
    }
}

template <typename RMA, typename RMB, typename Epi>
__device__ __forceinline__ void gemm_core_g(const char* __restrict__ A, RMA rma, int a_rows,
                                            const char* __restrict__ B, RMB rmb, int b_rows,
                                            int K, int row0, int col0, char* lds, Epi epi) {
    const int lane = threadIdx.x & 63;
    const int wave = threadIdx.x >> 6;
    const int wrow = (wave >> 1) * 64;
    const int wcol = (wave & 1) * 64;
    const int lr = lane & 15;
    const int kg = lane >> 4;
    const int nt = K >> 6;

    floatx4 acc[4][4];
#pragma unroll
    for (int i = 0; i < 4; ++i)
#pragma unroll
        for (int j = 0; j < 4; ++j) acc[i][j] = (floatx4){0.f, 0.f, 0.f, 0.f};

    stage_tile_g(A, rma, a_rows, row0, 0, lds);
    stage_tile_g(B, rmb, b_rows, col0, 0, lds + 16384);

    for (int t = 0; t < nt; ++t) {
        char* cur = lds + (t & 1) * 32768;
        if (t + 1 < nt) {
            char* nxt = lds + ((t + 1) & 1) * 32768;
            stage_tile_g(A, rma, a_rows, row0, (t + 1) << 7, nxt);
            stage_tile_g(B, rmb, b_rows, col0, (t + 1) << 7, nxt + 16384);
            asm volatile("s_waitcnt vmcnt(8)" ::: "memory");
        } else {
            asm volatile("s_waitcnt vmcnt(0)" ::: "memory");
        }
        __builtin_amdgcn_s_barrier();
#pragma unroll
        for (int ks = 0; ks < 2; ++ks) {
            short8 av[4], bv[4];
#pragma unroll
            for (int mi = 0; mi < 4; ++mi) {
                int row = wrow + mi * 16 + lr;
                int cb = (ks * 64 + kg * 16) ^ ((row & 7) << 4);
                av[mi] = *(const short8*)(cur + row * 128 + cb);
            }
#pragma unroll
            for (int ni = 0; ni < 4; ++ni) {
                int row = wcol + ni * 16 + lr;
                int cb = (ks * 64 + kg * 16) ^ ((row & 7) << 4);
                bv[ni] = *(const short8*)(cur + 16384 + row * 128 + cb);
            }
#pragma unroll
            for (int mi = 0; mi < 4; ++mi)
#pragma unroll
                for (int ni = 0; ni < 4; ++ni)
                    acc[mi][ni] = __builtin_amdgcn_mfma_f32_16x16x32_bf16(av[mi], bv[ni],
                                                                          acc[mi][ni], 0, 0, 0);
        }
        asm volatile("s_waitcnt lgkmcnt(0)" ::: "memory");
        __builtin_amdgcn_s_barrier();
    }
#pragma unroll
    for (int mi = 0; mi < 4; ++mi)
#pragma unroll
        for (int ni = 0; ni < 4; ++ni)
#pragma unroll
            for (int rr = 0; rr < 4; ++rr)
                epi(row0 + wrow + mi * 16 + kg * 4 + rr, col0 + wcol + ni * 16 + lr,
                    acc[mi][ni][rr]);
}

// scores[z][i][j] = q_scaled[i].k[j]  (bf16, cols padded to 256), z = local bnh
__global__ __launch_bounds__(256, 2) void k_qk(const u16* __restrict__ q,
                                               const u16* __restrict__ kvc,
                                               u16* __restrict__ sc, int bn0) {
    __shared__ __align__(128) char lds[65536];
    const int z = blockIdx.z, bnl = z >> 3, h = z & 7;
    const char* A = (const char*)(q + ((size_t)(bn0 + bnl) * CTX) * DMODEL + h * DH);
    const char* B = (const char*)(kvc + ((size_t)bnl * CTX) * (2 * DMODEL) + h * DH);
    u16* out = sc + (size_t)z * CTX * 256;
    gemm_core_g(A, [](int r) { return (size_t)r * (DMODEL * 2); }, CTX, B,
                [](int r) { return (size_t)r * (4 * DMODEL); }, CTX, DH, blockIdx.x * 128,
                blockIdx.y * 128, lds, [&](int r, int c, float v) {
                    if (r < CTX) out[(size_t)r * 256 + c] = f2bf(v);
                });
}

// scores[m][i][j] += q'[m].rel[i][j]  (batched over i; A gathered from q via row map)
__global__ __launch_bounds__(256, 2) void k_pos(const u16* __restrict__ q,
                                                const u16* __restrict__ rel,
                                                u16* __restrict__ sc, int m0) {
    __shared__ __align__(128) char lds[65536];
    const int i = blockIdx.z;
    const char* B = (const char*)(rel + (size_t)i * CTX * DH);
    u16* out = sc + i * 256;
    gemm_core_g((const char*)q,
                [=](int r) {
                    int m = m0 + r;
                    return (size_t)(((m >> 3) * CTX + i) * DMODEL + (m & 7) * DH) * 2;
                },
                AM, B, [](int r) { return (size_t)r * (DH * 2); }, CTX, DH, blockIdx.x * 128,
                blockIdx.y * 128, lds, [&](int r, int c, float v) {
                    if (r < AM) {
                        size_t idx = (size_t)r * (CTX * 256) + c;
                        out[idx] = f2bf(bf2f(out[idx]) + v);
                    }
                });
}

// attn_out[(bn0+z/8)*CTX+i][(z&7)*DH+dh] = P[z][i][:].vT[z][dh][:]  (K=256 padded)
__global__ __launch_bounds__(256, 2) void k_pv(const u16* __restrict__ P,
                                               const u16* __restrict__ vT,
                                               u16* __restrict__ attn, int bn0) {
    __shared__ __align__(128) char lds[65536];
    const int z = blockIdx.z;
    u16* out = attn + ((size_t)(bn0 + (z >> 3)) * CTX) * DMODEL + (z & 7) * DH;
    const char* A = (const char*)(P + (size_t)z * CTX * 256);
    const char* B = (const char*)(vT + (size_t)z * DH * 256);
    gemm_core_g(A, [](int r) { return (size_t)r * 512; }, CTX, B,
                [](int r) { return (size_t)r * 512; }, DH, 256, blockIdx.x * 128, 0, lds,
                [&](int r, int c, float v) {
                    if (r < CTX) out[(size_t)r * DMODEL + c] = f2bf(v);
                });
}

// ---------------- LayerNorm ----------------
template <bool OUTF32>
__global__ __launch_bounds__(256) void k_ln(const float* __restrict__ x,
                                            const float* __restrict__ g,
                                            const float* __restrict__ b, void* __restrict__ out) {
    const int row = blockIdx.x, t = threadIdx.x, lane = t & 63, wv = t >> 6;
    const float4 v = ((const float4*)(x + (size_t)row * DMODEL))[t];
    float s = v.x + v.y + v.z + v.w;
    float q = v.x * v.x + v.y * v.y + v.z * v.z + v.w * v.w;
#pragma unroll
    for (int off = 32; off > 0; off >>= 1) { s += __shfl_down(s, off); q += __shfl_down(q, off); }
    __shared__ float rs_[4], rq_[4];
    if (lane == 0) { rs_[wv] = s; rq_[wv] = q; }
    __syncthreads();
    s = rs_[0] + rs_[1] + rs_[2] + rs_[3];
    q = rq_[0] + rq_[1] + rq_[2] + rq_[3];
    const float mu = s * (1.f / DMODEL);
    const float rstd = rsqrtf(q * (1.f / DMODEL) - mu * mu + 1e-5f);
    const float4 gv = ((const float4*)g)[t];
    const float4 bv = ((const float4*)b)[t];
    float o0 = (v.x - mu) * rstd * gv.x + bv.x;
    float o1 = (v.y - mu) * rstd * gv.y + bv.y;
    float o2 = (v.z - mu) * rstd * gv.z + bv.z;
    float o3 = (v.w - mu) * rstd * gv.w + bv.w;
    if (OUTF32) {
        ((float4*)out)[(size_t)row * 256 + t] = make_float4(o0, o1, o2, o3);
    } else {
        ushort4 r4;
        r4.x = f2bf(o0); r4.y = f2bf(o1); r4.z = f2bf(o2); r4.w = f2bf(o3);
        ((ushort4*)out)[(size_t)row * 256 + t] = r4;
    }
}

// softmax over j, in-place on bf16 scores; zeroes pad cols [CTX,256)
__global__ __launch_bounds__(256) void k_softmax(u16* __restrict__ sc) {
    const size_t row = blockIdx.x;
    const int t = threadIdx.x, lane = t & 63, wv = t >> 6;
    float v = (t < CTX) ? bf2f(sc[row * 256 + t]) : -3.0e38f;
    float m = v;
#pragma unroll
    for (int off = 32; off > 0; off >>= 1) m = fmaxf(m, __shfl_down(m, off));
    __shared__ float rm[4], rsum[4];
    if (lane == 0) rm[wv] = m;
    __syncthreads();
    m = fmaxf(fmaxf(rm[0], rm[1]), fmaxf(rm[2], rm[3]));
    float e = (t < CTX) ? __expf(v - m) : 0.f;
    float s = e;
#pragma unroll
    for (int off = 32; off > 0; off >>= 1) s += __shfl_down(s, off);
    if (lane == 0) rsum[wv] = s;
    __syncthreads();
    s = rsum[0] + rsum[1] + rsum[2] + rsum[3];
    sc[row * 256 + t] = f2bf(e / s);
}

// GLU: a *= sigmoid(gate)
__global__ __launch_bounds__(256) void k_glu(u16* __restrict__ a, const u16* __restrict__ gate) {
    const size_t base = ((size_t)blockIdx.x * 256 + threadIdx.x) * 8;
    const short8 a8 = *(const short8*)(a + base);
    const short8 g8 = *(const short8*)(gate + base);
    short8 o8;
#pragma unroll
    for (int e = 0; e < 8; ++e) {
        float av = bf2f((u16)a8[e]), gg = bf2f((u16)g8[e]);
        o8[e] = (short)f2bf(av * sigmoidf_(gg));
    }
    *(short8*)(a + base) = o8;
}

// depthwise conv(K=15,pad=7)+BN(eval)+silu on [8][2000][1024] channel-slice; c0 = offset
__global__ __launch_bounds__(256) void k_dwconv(const u16* __restrict__ glu,
                                                const float* __restrict__ w,
                                                const float* __restrict__ bng,
                                                const float* __restrict__ bnb,
                                                const float* __restrict__ bnm,
                                                const float* __restrict__ bnv,
                                                u16* __restrict__ out, int c0) {
    const int b = blockIdx.z, lt = blockIdx.x, cg = blockIdx.y;
    const int c = cg * 256 + threadIdx.x;
    const int gc = c0 + c;
    const int l0 = lt * 16;
    __shared__ u16 s[30][256];
#pragma unroll
    for (int rr = 0; rr < 30; ++rr) {
        int l = l0 + rr - 7;
        u16 v = 0;
        if (l >= 0 && l < 2000) v = glu[((size_t)b * 2000 + l) * 1024 + c];
        s[rr][threadIdx.x] = v;
    }
    __syncthreads();
    float wv[15];
#pragma unroll
    for (int k = 0; k < 15; ++k) wv[k] = w[gc * 15 + k];
    const float sc = rsqrtf(bnv[gc] + 1e-5f) * bng[gc];
    const float mean = bnm[gc], bb = bnb[gc];
#pragma unroll
    for (int l = 0; l < 16; ++l) {
        float acc = 0.f;
#pragma unroll
        for (int k = 0; k < 15; ++k) acc += bf2f(s[l + k][threadIdx.x]) * wv[k];
        float h = (acc - mean) * sc + bb;
        h = h * sigmoidf_(h);
        out[((size_t)b * 2000 + l0 + l) * 1024 + c] = f2bf(h);
    }
}

// weight transpose f32[K,N] -> bf16[N,K]
__global__ __launch_bounds__(256) void k_wt(const float* __restrict__ w, u16* __restrict__ wt,
                                            int K, int N) {
    __shared__ float tile[32][33];
    const int k0 = blockIdx.x * 32, n0 = blockIdx.y * 32;
    const int tx = threadIdx.x & 31, ty = threadIdx.x >> 5;
#pragma unroll
    for (int i = 0; i < 32; i += 8) tile[ty + i][tx] = w[(size_t)(k0 + ty + i) * N + n0 + tx];
    __syncthreads();
#pragma unroll
    for (int i = 0; i < 32; i += 8)
        wt[(size_t)(n0 + ty + i) * K + k0 + tx] = f2bf(tile[tx][ty + i]);
}

// rel_bf16[i][j][dh] = bf16(rel_emb[dist[i][j]][dh])
__global__ void k_rel(const float* __restrict__ emb, const int* __restrict__ dist,
                      u16* __restrict__ rel) {
    const int bid = blockIdx.x;
    const int d = dist[bid];
    rel[(size_t)bid * DH + threadIdx.x] = f2bf(emb[(size_t)d * DH + threadIdx.x]);
}

// vT[z][dh][j] = v_chunk[bnl*CTX+j][DMODEL + h*DH + dh], zero-padded j in [CTX,256)
__global__ __launch_bounds__(256) void k_vt(const u16* __restrict__ kvc, u16* __restrict__ vT) {
    __shared__ u16 t_[64 * 130];
    const int z = blockIdx.x, jt = blockIdx.y;
    const int bnl = z >> 3, h = z & 7;
    const int j0 = jt * 64;
    for (int idx = threadIdx.x; idx < 8192; idx += 256) {
        int j = idx >> 7, dh = idx & 127;
        int jj = j0 + j;
        u16 val = 0;
        if (jj < CTX) val = kvc[((size_t)(bnl * CTX + jj)) * (2 * DMODEL) + DMODEL + h * DH + dh];
        t_[j * 130 + dh] = val;
    }
    __syncthreads();
    for (int idx = threadIdx.x; idx < 8192; idx += 256) {
        int dh = idx >> 6, j = idx & 63;
        vT[((size_t)z * DH + dh) * 256 + j0 + j] = t_[j * 130 + dh];
    }
}

__global__ void k_fill(float* o, int n, float v) {
    int i = blockIdx.x * 256 + threadIdx.x;
    if (i < n) o[i] = v;
}

extern "C" void kernel_launch(void* const* d_in, const int* in_sizes, int n_in, void* d_out,
                              int out_size, void* d_ws, size_t ws_size, hipStream_t stream) {
    const float* x_in = (const float*)d_in[0];
    const int* dists = (const int*)d_in[1];
    const float* ff1_ln_g = (const float*)d_in[2];
    const float* ff1_ln_b = (const float*)d_in[3];
    const float* ff1_up_w = (const float*)d_in[4];
    const float* ff1_up_b = (const float*)d_in[5];
    const float* ff1_down_w = (const float*)d_in[6];
    const float* ff1_down_b = (const float*)d_in[7];
    const float* attn_ln_g = (const float*)d_in[8];
    const float* attn_ln_b = (const float*)d_in[9];
    const float* wq = (const float*)d_in[10];
    const float* wkv = (const float*)d_in[11];
    const float* wo = (const float*)d_in[12];
    const float* wo_b = (const float*)d_in[13];
    const float* rel_emb = (const float*)d_in[14];
    const float* conv_ln_g = (const float*)d_in[15];
    const float* conv_ln_b = (const float*)d_in[16];
    const float* conv_up_w = (const float*)d_in[17];
    const float* conv_up_b = (const float*)d_in[18];
    const float* dw_w = (const float*)d_in[19];
    const float* bn_g = (const float*)d_in[20];
    const float* bn_b = (const float*)d_in[21];
    const float* bn_mean = (const float*)d_in[22];
    const float* bn_var = (const float*)d_in[23];
    const float* conv_down_w = (const float*)d_in[24];
    const float* conv_down_b = (const float*)d_in[25];
    const float* ff2_ln_g = (const float*)d_in[26];
    const float* ff2_ln_b = (const float*)d_in[27];
    const float* ff2_up_w = (const float*)d_in[28];
    const float* ff2_up_b = (const float*)d_in[29];
    const float* ff2_down_w = (const float*)d_in[30];
    const float* ff2_down_b = (const float*)d_in[31];
    const float* post_ln_g = (const float*)d_in[32];
    const float* post_ln_b = (const float*)d_in[33];

    char* W = (char*)d_ws;
    size_t off = 0;
    auto alloc = [&](size_t bytes) {
        char* p = W + off;
        off += (bytes + 255) & ~(size_t)255;
        return (u16*)p;
    };
    u16* slotA = alloc((size_t)4096 * 1024 * 2);        // up / q / kv / wo weights
    u16* slotB = alloc((size_t)4096 * 1024 * 2);        // down weights
    u16* rel_bf = alloc((size_t)CTX * CTX * DH * 2);    // 10.2 MB
    u16* ln_buf = alloc((size_t)R_TOT * DMODEL * 2);    // 32.8 MB
    u16* bufA = alloc((size_t)AROWS * 2 * DMODEL * 2);  // 32.8 MB  kv / gate / conv-out
    u16* bufB = alloc((size_t)R_TOT * DMODEL * 2);      // 32.8 MB  q / attn_out
    u16* smid = alloc((size_t)R_TOT * DMODEL * 2);      // 32.8 MB  FF-mid-slice / scores / glu-a
    u16* vT = alloc((size_t)AM * DH * 256 * 2);         // 21.0 MB
    float* xs = (float*)d_out;                          // f32 residual stream in d_out

    if (ws_size < off) {  // sentinel: absmax ~= 31337 means ws too small
        k_fill<<<(out_size + 255) / 256, 256, 0, stream>>>((float*)d_out, out_size, 31337.f);
        return;
    }

    auto WT = [&](const float* s, u16* d, int K, int N) {
        k_wt<<<dim3(K / 32, N / 32), 256, 0, stream>>>(s, d, K, N);
    };
    auto G256 = [&](int M, int N) { return dim3((M + 255) / 256, N / 256); };

    k_rel<<<CTX * CTX, 128, 0, stream>>>(rel_emb, dists, rel_bf);

    // ---- FF helper: x = 0.5*(silu(ln@Wup+bu)@Wdn + bd) + resid, K-split into 4 slices ----
    auto ff_block = [&](const float* lng, const float* lnb, const float* upb,
                        const float* dnb, const float* resid0, const float* xsrc) {
        k_ln<false><<<R_TOT, 256, 0, stream>>>(xsrc, lng, lnb, ln_buf);
        for (int kc = 0; kc < 4; ++kc) {
            k_gemm256<1><<<G256(R_TOT, 1024), 512, 0, stream>>>(
                ln_buf, DMODEL, slotA + (size_t)kc * 1024 * 1024, DMODEL, upb + kc * 1024, 1.f,
                smid, DMODEL, nullptr, R_TOT, DMODEL, DMODEL);
            if (kc == 0)
                k_gemm256<2><<<G256(R_TOT, 1024), 512, 0, stream>>>(
                    smid, DMODEL, slotB + kc * 1024, DFF, dnb, 0.5f, xs, DMODEL, resid0, R_TOT,
                    DMODEL, DMODEL);
            else
                k_gemm256<3><<<G256(R_TOT, 1024), 512, 0, stream>>>(
                    smid, DMODEL, slotB + kc * 1024, DFF, nullptr, 0.5f, xs, DMODEL, nullptr,
                    R_TOT, DMODEL, DMODEL);
        }
    };

    // ---- FF1 ----
    WT(ff1_up_w, slotA, 1024, 4096);
    WT(ff1_down_w, slotB, 4096, 1024);
    ff_block(ff1_ln_g, ff1_ln_b, ff1_up_b, ff1_down_b, x_in, x_in);

    // ---- Attention ----
    k_ln<false><<<R_TOT, 256, 0, stream>>>(xs, attn_ln_g, attn_ln_b, ln_buf);
    WT(wq, slotA, 1024, 1024);
    k_gemm256<0><<<G256(R_TOT, 1024), 512, 0, stream>>>(ln_buf, DMODEL, slotA, DMODEL, nullptr,
                                                        SCALE_Q, bufB, DMODEL, nullptr, R_TOT,
                                                        DMODEL, DMODEL);
    WT(wkv, slotA, 1024, 2048);
    for (int h = 0; h < 2; ++h) {
        const int bn0 = h * ABN, m0 = bn0 * 8;
        const u16* lnc = ln_buf + (size_t)bn0 * CTX * DMODEL;
        k_gemm256<0><<<G256(AROWS, 2048), 512, 0, stream>>>(lnc, DMODEL, slotA, DMODEL, nullptr,
                                                            1.f, bufA, 2 * DMODEL, nullptr,
                                                            AROWS, 2 * DMODEL, DMODEL);
        k_vt<<<dim3(AM, 4), 256, 0, stream>>>(bufA, vT);
        k_qk<<<dim3(2, 2, AM), 256, 0, stream>>>(bufB, bufA, smid, bn0);
        k_pos<<<dim3(3, 2, CTX), 256, 0, stream>>>(bufB, rel_bf, smid, m0);
        k_softmax<<<AM * CTX, 256, 0, stream>>>(smid);
        k_pv<<<dim3(2, 1, AM), 256, 0, stream>>>(smid, vT, bufB, bn0);
    }
    WT(wo, slotA, 1024, 1024);
    k_gemm256<2><<<G256(R_TOT, 1024), 512, 0, stream>>>(bufB, DMODEL, slotA, DMODEL, wo_b, 1.f,
                                                        xs, DMODEL, xs, R_TOT, DMODEL, DMODEL);

    // ---- Conv module (2 channel-slices of 1024) ----
    k_ln<false><<<R_TOT, 256, 0, stream>>>(xs, conv_ln_g, conv_ln_b, ln_buf);
    WT(conv_up_w, slotA, 1024, 4096);
    WT(conv_down_w, slotB, 2048, 1024);
    for (int kc = 0; kc < 2; ++kc) {
        k_gemm256<0><<<G256(R_TOT, 1024), 512, 0, stream>>>(
            ln_buf, DMODEL, slotA + (size_t)kc * 1024 * 1024, DMODEL, conv_up_b + kc * 1024, 1.f,
            smid, DMODEL, nullptr, R_TOT, DMODEL, DMODEL);
        k_gemm256<0><<<G256(R_TOT, 1024), 512, 0, stream>>>(
            ln_buf, DMODEL, slotA + (size_t)(2048 + kc * 1024) * 1024, DMODEL,
            conv_up_b + 2048 + kc * 1024, 1.f, bufA, DMODEL, nullptr, R_TOT, DMODEL, DMODEL);
        k_glu<<<R_TOT * DMODEL / 8 / 256, 256, 0, stream>>>(smid, bufA);
        k_dwconv<<<dim3(125, 4, 8), 256, 0, stream>>>(smid, dw_w, bn_g, bn_b, bn_mean, bn_var,
                                                      bufA, kc * 1024);
        if (kc == 0)
            k_gemm256<2><<<G256(R_TOT, 1024), 512, 0, stream>>>(bufA, DMODEL, slotB + kc * 1024,
                                                                INNER, conv_down_b, 1.f, xs,
                                                                DMODEL, xs, R_TOT, DMODEL,
                                                                DMODEL);
        else
            k_gemm256<3><<<G256(R_TOT, 1024), 512, 0, stream>>>(bufA, DMODEL, slotB + kc * 1024,
                                                                INNER, nullptr, 1.f, xs, DMODEL,
                                                                nullptr, R_TOT, DMODEL, DMODEL);
    }

    // ---- FF2 ----
    WT(ff2_up_w, slotA, 1024, 4096);
    WT(ff2_down_w, slotB, 4096, 1024);
    ff_block(ff2_ln_g, ff2_ln_b, ff2_up_b, ff2_down_b, xs, xs);

    // ---- final LayerNorm (in-place on d_out) ----
    k_ln<true><<<R_TOT, 256, 0, stream>>>(xs, post_ln_g, post_ln_b, d_out);
}

// Round 5
// 1972.640 us; speedup vs baseline: 1.2456x; 1.1547x over previous
//
#include <hip/hip_runtime.h>

typedef unsigned short u16;
typedef unsigned int u32;
using short8 = __attribute__((ext_vector_type(8))) short;
using floatx4 = __attribute__((ext_vector_type(4))) float;

#define DMODEL 1024
#define DFF 4096
#define INNER 2048
#define DH 128
#define CTX 200
#define R_TOT 16000
#define ABN 40  // attention bn per chunk (2 chunks)
#define AROWS (ABN * CTX)
#define AM (ABN * 8)
#define SCALE_Q 0.08838834764831845f

__device__ __forceinline__ u16 f2bf(float f) {
    union { float f; u32 u; } v; v.f = f;
    u32 r = v.u + 0x7FFFu + ((v.u >> 16) & 1u);
    return (u16)(r >> 16);
}
__device__ __forceinline__ float bf2f(u16 u) {
    union { u32 u; float f; } v; v.u = ((u32)u) << 16; return v.f;
}
__device__ __forceinline__ float sigmoidf_(float x) { return 1.f / (1.f + __expf(-x)); }

__device__ __forceinline__ void load_lds16(const void* g, void* l) {
    __builtin_amdgcn_global_load_lds((const __attribute__((address_space(1))) u32*)g,
                                     (__attribute__((address_space(3))) u32*)l, 16, 0, 0);
}

// ============== 256x256 tile GEMM: BK=64, 8 waves (2Mx4N), T3 2-phase ==============
// Stage [256 rows][64 k] bf16 (32 KB); XOR swizzle ((row&7)<<4) pre-applied on the per-lane
// GLOBAL source address (LDS dst linear). 4 loads/thread (512 threads).
template <typename RowMap>
__device__ __forceinline__ void stage256(const char* __restrict__ src, RowMap rowoff, int nrows,
                                         int row0, int k0b, char* dst) {
    const int lane = threadIdx.x & 63;
    const int wave = threadIdx.x >> 6;
#pragma unroll
    for (int r = 0; r < 4; ++r) {
        int o = r * 8192 + wave * 1024 + lane * 16;
        int row = o >> 7;
        int srcb = (o & 127) ^ ((row & 7) << 4);
        int grow = row0 + row;
        grow = (grow < nrows) ? grow : (nrows - 1);
        const char* g = src + rowoff(grow) + k0b + srcb;
        load_lds16(g, dst + r * 8192 + wave * 1024);
    }
}

// T3 recipe (m230, 682 TF verified structure): per K-tile
//   STAGE(nxt) ; ds_read cur ; setprio(1) MFMA setprio(0) ; lgkmcnt(0) ; vmcnt(0) ; barrier
// Loads for tile t+1 fly UNDER tile t's compute; ONE barrier per K-tile.
template <typename RMA, typename RMB, typename Epi>
__device__ __forceinline__ void gemm256_core(const char* __restrict__ A, RMA rma, int a_rows,
                                             const char* __restrict__ B, RMB rmb, int b_rows,
                                             int K, int row0, int col0, char* lds, Epi epi) {
    const int lane = threadIdx.x & 63;
    const int wave = threadIdx.x >> 6;
    const int wrow = (wave >> 2) * 128;
    const int wcol = (wave & 3) * 64;
    const int lr = lane & 15;
    const int kg = lane >> 4;
    const int nt = K >> 6;

    floatx4 acc[8][4];
#pragma unroll
    for (int i = 0; i < 8; ++i)
#pragma unroll
        for (int j = 0; j < 4; ++j) acc[i][j] = (floatx4){0.f, 0.f, 0.f, 0.f};

    stage256(A, rma, a_rows, row0, 0, lds);
    stage256(B, rmb, b_rows, col0, 0, lds + 32768);
    asm volatile("s_waitcnt vmcnt(0)" ::: "memory");
    __builtin_amdgcn_s_barrier();

    for (int t = 0; t < nt; ++t) {
        char* cur = lds + (t & 1) * 65536;
        char* nxt = lds + ((t + 1) & 1) * 65536;
        if (t + 1 < nt) {
            stage256(A, rma, a_rows, row0, (t + 1) << 7, nxt);
            stage256(B, rmb, b_rows, col0, (t + 1) << 7, nxt + 32768);
        }
#pragma unroll
        for (int ks = 0; ks < 2; ++ks) {
            short8 av[8], bv[4];
#pragma unroll
            for (int mi = 0; mi < 8; ++mi) {
                int row = wrow + mi * 16 + lr;
                int cb = (ks * 64 + kg * 16) ^ ((row & 7) << 4);
                av[mi] = *(const short8*)(cur + row * 128 + cb);
            }
#pragma unroll
            for (int ni = 0; ni < 4; ++ni) {
                int row = wcol + ni * 16 + lr;
                int cb = (ks * 64 + kg * 16) ^ ((row & 7) << 4);
                bv[ni] = *(const short8*)(cur + 32768 + row * 128 + cb);
            }
            __builtin_amdgcn_s_setprio(1);
#pragma unroll
            for (int mi = 0; mi < 8; ++mi)
#pragma unroll
                for (int ni = 0; ni < 4; ++ni)
                    acc[mi][ni] = __builtin_amdgcn_mfma_f32_16x16x32_bf16(av[mi], bv[ni],
                                                                          acc[mi][ni], 0, 0, 0);
            __builtin_amdgcn_s_setprio(0);
        }
        if (t + 1 < nt)
            asm volatile("s_waitcnt vmcnt(0) lgkmcnt(0)" ::: "memory");
        else
            asm volatile("s_waitcnt lgkmcnt(0)" ::: "memory");
        __builtin_amdgcn_sched_barrier(0);
        __builtin_amdgcn_s_barrier();
    }
#pragma unroll
    for (int mi = 0; mi < 8; ++mi)
#pragma unroll
        for (int ni = 0; ni < 4; ++ni)
#pragma unroll
            for (int rr = 0; rr < 4; ++rr)
                epi(row0 + wrow + mi * 16 + kg * 4 + rr, col0 + wcol + ni * 16 + lr,
                    acc[mi][ni][rr]);
}

// bijective XCD-chunked remap (m204)
__device__ __forceinline__ void xcd_remap(int& bx, int& by) {
    const int gx = gridDim.x, nwg = gx * gridDim.y;
    const int orig = blockIdx.y * gx + blockIdx.x;
    const int q = nwg >> 3, r = nwg & 7, xcd = orig & 7;
    const int base = (xcd < r) ? xcd * (q + 1) : r * (q + 1) + (xcd - r) * q;
    const int wgid = base + (orig >> 3);
    bx = wgid % gx;
    by = wgid / gx;
}

// MODE 0: bf16 out = alpha*v + bias ; MODE 1: bf16 out = silu(v+bias) ;
// MODE 2: f32 out = alpha*(v+bias) + resid
template <int MODE>
__global__ __launch_bounds__(512, 2) void k_gemm256(const u16* __restrict__ A, int lda,
                                                    const u16* __restrict__ Bt, int ldb,
                                                    const float* __restrict__ bias, float alpha,
                                                    void* out, int ldc, const float* resid,
                                                    int M, int N, int K) {
    __shared__ __align__(128) char lds[131072];
    int bx, by;
    xcd_remap(bx, by);
    const int row0 = bx * 256, col0 = by * 256;
    u16* ob = (u16*)out;
    float* of = (float*)out;
    const size_t la = (size_t)lda * 2, lb = (size_t)ldb * 2;
    gemm256_core((const char*)A, [=](int r) { return (size_t)r * la; }, M,
                 (const char*)Bt, [=](int r) { return (size_t)r * lb; }, N, K, row0, col0, lds,
                 [&](int r, int c, float v) {
                     if (r >= M) return;
                     size_t idx = (size_t)r * ldc + c;
                     float bb = bias ? bias[c] : 0.f;
                     if (MODE == 0) {
                         ob[idx] = f2bf(alpha * v + bb);
                     } else if (MODE == 1) {
                         float t = v + bb;
                         ob[idx] = f2bf(t * sigmoidf_(t));
                     } else {
                         of[idx] = alpha * (v + bb) + resid[idx];
                     }
                 });
}

// ============== 128x128 tile core (attention-internal GEMMs), same T3 pipeline ==========
template <typename RowMap>
__device__ __forceinline__ void stage_tile_g(const char* __restrict__ src, RowMap rowoff,
                                             int nrows, int row0, int k0b, char* tile) {
    const int lane = threadIdx.x & 63;
    const int wave = threadIdx.x >> 6;
#pragma unroll
    for (int r = 0; r < 4; ++r) {
        int o = r * 4096 + wave * 1024 + lane * 16;
        int row = o >> 7;
        int srcb = (o & 127) ^ ((row & 7) << 4);
        int grow = row0 + row;
        grow = (grow < nrows) ? grow : (nrows - 1);
        const char* g = src + rowoff(grow) + k0b + srcb;
        load_lds16(g, tile + r * 4096 + wave * 1024);
    }
}

template <typename RMA, typename RMB, typename Epi>
__device__ __forceinline__ void gemm_core_g(const char* __restrict__ A, RMA rma, int a_rows,
                                            const char* __restrict__ B, RMB rmb, int b_rows,
                                            int K, int row0, int col0, char* lds, Epi epi) {
    const int lane = threadIdx.x & 63;
    const int wave = threadIdx.x >> 6;
    const int wrow = (wave >> 1) * 64;
    const int wcol = (wave & 1) * 64;
    const int lr = lane & 15;
    const int kg = lane >> 4;
    const int nt = K >> 6;

    floatx4 acc[4][4];
#pragma unroll
    for (int i = 0; i < 4; ++i)
#pragma unroll
        for (int j = 0; j < 4; ++j) acc[i][j] = (floatx4){0.f, 0.f, 0.f, 0.f};

    stage_tile_g(A, rma, a_rows, row0, 0, lds);
    stage_tile_g(B, rmb, b_rows, col0, 0, lds + 16384);
    asm volatile("s_waitcnt vmcnt(0)" ::: "memory");
    __builtin_amdgcn_s_barrier();

    for (int t = 0; t < nt; ++t) {
        char* cur = lds + (t & 1) * 32768;
        char* nxt = lds + ((t + 1) & 1) * 32768;
        if (t + 1 < nt) {
            stage_tile_g(A, rma, a_rows, row0, (t + 1) << 7, nxt);
            stage_tile_g(B, rmb, b_rows, col0, (t + 1) << 7, nxt + 16384);
        }
#pragma unroll
        for (int ks = 0; ks < 2; ++ks) {
            short8 av[4], bv[4];
#pragma unroll
            for (int mi = 0; mi < 4; ++mi) {
                int row = wrow + mi * 16 + lr;
                int cb = (ks * 64 + kg * 16) ^ ((row & 7) << 4);
                av[mi] = *(const short8*)(cur + row * 128 + cb);
            }
#pragma unroll
            for (int ni = 0; ni < 4; ++ni) {
                int row = wcol + ni * 16 + lr;
                int cb = (ks * 64 + kg * 16) ^ ((row & 7) << 4);
                bv[ni] = *(const short8*)(cur + 16384 + row * 128 + cb);
            }
            __builtin_amdgcn_s_setprio(1);
#pragma unroll
            for (int mi = 0; mi < 4; ++mi)
#pragma unroll
                for (int ni = 0; ni < 4; ++ni)
                    acc[mi][ni] = __builtin_amdgcn_mfma_f32_16x16x32_bf16(av[mi], bv[ni],
                                                                          acc[mi][ni], 0, 0, 0);
            __builtin_amdgcn_s_setprio(0);
        }
        if (t + 1 < nt)
            asm volatile("s_waitcnt vmcnt(0) lgkmcnt(0)" ::: "memory");
        else
            asm volatile("s_waitcnt lgkmcnt(0)" ::: "memory");
        __builtin_amdgcn_sched_barrier(0);
        __builtin_amdgcn_s_barrier();
    }
#pragma unroll
    for (int mi = 0; mi < 4; ++mi)
#pragma unroll
        for (int ni = 0; ni < 4; ++ni)
#pragma unroll
            for (int rr = 0; rr < 4; ++rr)
                epi(row0 + wrow + mi * 16 + kg * 4 + rr, col0 + wcol + ni * 16 + lr,
                    acc[mi][ni][rr]);
}

// scores[z][i][j] = q_scaled[i].k[j]  (bf16, cols padded to 256), z = local bnh
__global__ __launch_bounds__(256, 2) void k_qk(const u16* __restrict__ q,
                                               const u16* __restrict__ kvc,
                                               u16* __restrict__ sc, int bn0) {
    __shared__ __align__(128) char lds[65536];
    const int z = blockIdx.z, bnl = z >> 3, h = z & 7;
    const char* A = (const char*)(q + ((size_t)(bn0 + bnl) * CTX) * DMODEL + h * DH);
    const char* B = (const char*)(kvc + ((size_t)bnl * CTX) * (2 * DMODEL) + h * DH);
    u16* out = sc + (size_t)z * CTX * 256;
    gemm_core_g(A, [](int r) { return (size_t)r * (DMODEL * 2); }, CTX, B,
                [](int r) { return (size_t)r * (4 * DMODEL); }, CTX, DH, blockIdx.x * 128,
                blockIdx.y * 128, lds, [&](int r, int c, float v) {
                    if (r < CTX) out[(size_t)r * 256 + c] = f2bf(v);
                });
}

// scores[m][i][j] += q'[m].rel[i][j]  (batched over i; A gathered from q via row map)
__global__ __launch_bounds__(256, 2) void k_pos(const u16* __restrict__ q,
                                                const u16* __restrict__ rel,
                                                u16* __restrict__ sc, int m0) {
    __shared__ __align__(128) char lds[65536];
    const int i = blockIdx.z;
    const char* B = (const char*)(rel + (size_t)i * CTX * DH);
    u16* out = sc + i * 256;
    gemm_core_g((const char*)q,
                [=](int r) {
                    int m = m0 + r;
                    return (size_t)(((m >> 3) * CTX + i) * DMODEL + (m & 7) * DH) * 2;
                },
                AM, B, [](int r) { return (size_t)r * (DH * 2); }, CTX, DH, blockIdx.x * 128,
                blockIdx.y * 128, lds, [&](int r, int c, float v) {
                    if (r < AM) {
                        size_t idx = (size_t)r * (CTX * 256) + c;
                        out[idx] = f2bf(bf2f(out[idx]) + v);
                    }
                });
}

// attn_out[(bn0+z/8)*CTX+i][(z&7)*DH+dh] = P[z][i][:].vT[z][dh][:]  (K=256 padded)
__global__ __launch_bounds__(256, 2) void k_pv(const u16* __restrict__ P,
                                               const u16* __restrict__ vT,
                                               u16* __restrict__ attn, int bn0) {
    __shared__ __align__(128) char lds[65536];
    const int z = blockIdx.z;
    u16* out = attn + ((size_t)(bn0 + (z >> 3)) * CTX) * DMODEL + (z & 7) * DH;
    const char* A = (const char*)(P + (size_t)z * CTX * 256);
    const char* B = (const char*)(vT + (size_t)z * DH * 256);
    gemm_core_g(A, [](int r) { return (size_t)r * 512; }, CTX, B,
                [](int r) { return (size_t)r * 512; }, DH, 256, blockIdx.x * 128, 0, lds,
                [&](int r, int c, float v) {
                    if (r < CTX) out[(size_t)r * DMODEL + c] = f2bf(v);
                });
}

// ---------------- LayerNorm ----------------
template <bool OUTF32>
__global__ __launch_bounds__(256) void k_ln(const float* __restrict__ x,
                                            const float* __restrict__ g,
                                            const float* __restrict__ b, void* __restrict__ out) {
    const int row = blockIdx.x, t = threadIdx.x, lane = t & 63, wv = t >> 6;
    const float4 v = ((const float4*)(x + (size_t)row * DMODEL))[t];
    float s = v.x + v.y + v.z + v.w;
    float q = v.x * v.x + v.y * v.y + v.z * v.z + v.w * v.w;
#pragma unroll
    for (int off = 32; off > 0; off >>= 1) { s += __shfl_down(s, off); q += __shfl_down(q, off); }
    __shared__ float rs_[4], rq_[4];
    if (lane == 0) { rs_[wv] = s; rq_[wv] = q; }
    __syncthreads();
    s = rs_[0] + rs_[1] + rs_[2] + rs_[3];
    q = rq_[0] + rq_[1] + rq_[2] + rq_[3];
    const float mu = s * (1.f / DMODEL);
    const float rstd = rsqrtf(q * (1.f / DMODEL) - mu * mu + 1e-5f);
    const float4 gv = ((const float4*)g)[t];
    const float4 bv = ((const float4*)b)[t];
    float o0 = (v.x - mu) * rstd * gv.x + bv.x;
    float o1 = (v.y - mu) * rstd * gv.y + bv.y;
    float o2 = (v.z - mu) * rstd * gv.z + bv.z;
    float o3 = (v.w - mu) * rstd * gv.w + bv.w;
    if (OUTF32) {
        ((float4*)out)[(size_t)row * 256 + t] = make_float4(o0, o1, o2, o3);
    } else {
        ushort4 r4;
        r4.x = f2bf(o0); r4.y = f2bf(o1); r4.z = f2bf(o2); r4.w = f2bf(o3);
        ((ushort4*)out)[(size_t)row * 256 + t] = r4;
    }
}

// softmax over j, in-place on bf16 scores; zeroes pad cols [CTX,256)
__global__ __launch_bounds__(256) void k_softmax(u16* __restrict__ sc) {
    const size_t row = blockIdx.x;
    const int t = threadIdx.x, lane = t & 63, wv = t >> 6;
    float v = (t < CTX) ? bf2f(sc[row * 256 + t]) : -3.0e38f;
    float m = v;
#pragma unroll
    for (int off = 32; off > 0; off >>= 1) m = fmaxf(m, __shfl_down(m, off));
    __shared__ float rm[4], rsum[4];
    if (lane == 0) rm[wv] = m;
    __syncthreads();
    m = fmaxf(fmaxf(rm[0], rm[1]), fmaxf(rm[2], rm[3]));
    float e = (t < CTX) ? __expf(v - m) : 0.f;
    float s = e;
#pragma unroll
    for (int off = 32; off > 0; off >>= 1) s += __shfl_down(s, off);
    if (lane == 0) rsum[wv] = s;
    __syncthreads();
    s = rsum[0] + rsum[1] + rsum[2] + rsum[3];
    sc[row * 256 + t] = f2bf(e / s);
}

// GLU over mid[16000][4096]: a = cols [0,2048), gate = cols [2048,4096); in-place on a
__global__ __launch_bounds__(256) void k_glu(u16* __restrict__ mid) {
    const size_t r = blockIdx.x;
    const int c = threadIdx.x * 8;
    const short8 a8 = *(const short8*)(mid + r * 4096 + c);
    const short8 g8 = *(const short8*)(mid + r * 4096 + 2048 + c);
    short8 o8;
#pragma unroll
    for (int e = 0; e < 8; ++e) {
        float av = bf2f((u16)a8[e]), gg = bf2f((u16)g8[e]);
        o8[e] = (short)f2bf(av * sigmoidf_(gg));
    }
    *(short8*)(mid + r * 4096 + c) = o8;
}

// depthwise conv(K=15,pad=7)+BN(eval)+silu ; in = a-region (ld 4096), out = gate-region
__global__ __launch_bounds__(256) void k_dwconv(const u16* __restrict__ in,
                                                const float* __restrict__ w,
                                                const float* __restrict__ bng,
                                                const float* __restrict__ bnb,
                                                const float* __restrict__ bnm,
                                                const float* __restrict__ bnv,
                                                u16* __restrict__ out) {
    const int b = blockIdx.z, lt = blockIdx.x, cg = blockIdx.y;
    const int c = cg * 256 + threadIdx.x;  // 0..2047
    const int l0 = lt * 16;
    __shared__ u16 s[30][256];
#pragma unroll
    for (int rr = 0; rr < 30; ++rr) {
        int l = l0 + rr - 7;
        u16 v = 0;
        if (l >= 0 && l < 2000) v = in[((size_t)b * 2000 + l) * 4096 + c];
        s[rr][threadIdx.x] = v;
    }
    __syncthreads();
    float wv[15];
#pragma unroll
    for (int k = 0; k < 15; ++k) wv[k] = w[c * 15 + k];
    const float sc = rsqrtf(bnv[c] + 1e-5f) * bng[c];
    const float mean = bnm[c], bb = bnb[c];
#pragma unroll
    for (int l = 0; l < 16; ++l) {
        float acc = 0.f;
#pragma unroll
        for (int k = 0; k < 15; ++k) acc += bf2f(s[l + k][threadIdx.x]) * wv[k];
        float h = (acc - mean) * sc + bb;
        h = h * sigmoidf_(h);
        out[((size_t)b * 2000 + l0 + l) * 4096 + c] = f2bf(h);
    }
}

// weight transpose f32[K,N] -> bf16[N,K]
__global__ __launch_bounds__(256) void k_wt(const float* __restrict__ w, u16* __restrict__ wt,
                                            int K, int N) {
    __shared__ float tile[32][33];
    const int k0 = blockIdx.x * 32, n0 = blockIdx.y * 32;
    const int tx = threadIdx.x & 31, ty = threadIdx.x >> 5;
#pragma unroll
    for (int i = 0; i < 32; i += 8) tile[ty + i][tx] = w[(size_t)(k0 + ty + i) * N + n0 + tx];
    __syncthreads();
#pragma unroll
    for (int i = 0; i < 32; i += 8)
        wt[(size_t)(n0 + ty + i) * K + k0 + tx] = f2bf(tile[tx][ty + i]);
}

// rel_bf16[i][j][dh] = bf16(rel_emb[dist[i][j]][dh])
__global__ void k_rel(const float* __restrict__ emb, const int* __restrict__ dist,
                      u16* __restrict__ rel) {
    const int bid = blockIdx.x;
    const int d = dist[bid];
    rel[(size_t)bid * DH + threadIdx.x] = f2bf(emb[(size_t)d * DH + threadIdx.x]);
}

// vT[z][dh][j] = v_chunk[bnl*CTX+j][DMODEL + h*DH + dh], zero-padded j in [CTX,256)
__global__ __launch_bounds__(256) void k_vt(const u16* __restrict__ kvc, u16* __restrict__ vT) {
    __shared__ u16 t_[64 * 130];
    const int z = blockIdx.x, jt = blockIdx.y;
    const int bnl = z >> 3, h = z & 7;
    const int j0 = jt * 64;
    for (int idx = threadIdx.x; idx < 8192; idx += 256) {
        int j = idx >> 7, dh = idx & 127;
        int jj = j0 + j;
        u16 val = 0;
        if (jj < CTX) val = kvc[((size_t)(bnl * CTX + jj)) * (2 * DMODEL) + DMODEL + h * DH + dh];
        t_[j * 130 + dh] = val;
    }
    __syncthreads();
    for (int idx = threadIdx.x; idx < 8192; idx += 256) {
        int dh = idx >> 6, j = idx & 63;
        vT[((size_t)z * DH + dh) * 256 + j0 + j] = t_[j * 130 + dh];
    }
}

__global__ void k_fill(float* o, int n, float v) {
    int i = blockIdx.x * 256 + threadIdx.x;
    if (i < n) o[i] = v;
}

extern "C" void kernel_launch(void* const* d_in, const int* in_sizes, int n_in, void* d_out,
                              int out_size, void* d_ws, size_t ws_size, hipStream_t stream) {
    const float* x_in = (const float*)d_in[0];
    const int* dists = (const int*)d_in[1];
    const float* ff1_ln_g = (const float*)d_in[2];
    const float* ff1_ln_b = (const float*)d_in[3];
    const float* ff1_up_w = (const float*)d_in[4];
    const float* ff1_up_b = (const float*)d_in[5];
    const float* ff1_down_w = (const float*)d_in[6];
    const float* ff1_down_b = (const float*)d_in[7];
    const float* attn_ln_g = (const float*)d_in[8];
    const float* attn_ln_b = (const float*)d_in[9];
    const float* wq = (const float*)d_in[10];
    const float* wkv = (const float*)d_in[11];
    const float* wo = (const float*)d_in[12];
    const float* wo_b = (const float*)d_in[13];
    const float* rel_emb = (const float*)d_in[14];
    const float* conv_ln_g = (const float*)d_in[15];
    const float* conv_ln_b = (const float*)d_in[16];
    const float* conv_up_w = (const float*)d_in[17];
    const float* conv_up_b = (const float*)d_in[18];
    const float* dw_w = (const float*)d_in[19];
    const float* bn_g = (const float*)d_in[20];
    const float* bn_b = (const float*)d_in[21];
    const float* bn_mean = (const float*)d_in[22];
    const float* bn_var = (const float*)d_in[23];
    const float* conv_down_w = (const float*)d_in[24];
    const float* conv_down_b = (const float*)d_in[25];
    const float* ff2_ln_g = (const float*)d_in[26];
    const float* ff2_ln_b = (const float*)d_in[27];
    const float* ff2_up_w = (const float*)d_in[28];
    const float* ff2_up_b = (const float*)d_in[29];
    const float* ff2_down_w = (const float*)d_in[30];
    const float* ff2_down_b = (const float*)d_in[31];
    const float* post_ln_g = (const float*)d_in[32];
    const float* post_ln_b = (const float*)d_in[33];

    char* W = (char*)d_ws;
    size_t off = 0;
    auto alloc = [&](size_t bytes) {
        char* p = W + off;
        off += (bytes + 255) & ~(size_t)255;
        return (u16*)p;
    };
    // single weight slot: stream-serial reuse (WT -> GEMM -> WT -> GEMM ...)
    u16* slot = alloc((size_t)4096 * 1024 * 2);              // 8.4 MB
    u16* ln_buf = alloc((size_t)R_TOT * DMODEL * 2);         // 32.8 MB
    u16* arena = alloc((size_t)R_TOT * DFF * 2);             // 131.1 MB
    // arena aliases: FF/conv mid[16000][4096]  OR  attention {rel,kv,q,scores,vT}
    u16* mid = arena;
    u16* rel_bf = arena;                                     // 10.24 MB
    u16* bufA = rel_bf + (size_t)CTX * CTX * DH;             // kv chunk, 32.8 MB
    u16* bufB = bufA + (size_t)AROWS * 2 * DMODEL;           // q / attn_out, 32.8 MB
    u16* smid = bufB + (size_t)R_TOT * DMODEL;               // scores, 32.8 MB
    u16* vT = smid + (size_t)AM * CTX * 256;                 // 21.0 MB
    float* xs = (float*)d_out;                               // f32 residual stream in d_out

    if (ws_size < off) {  // sentinel: absmax ~= 31337 means ws too small
        k_fill<<<(out_size + 255) / 256, 256, 0, stream>>>((float*)d_out, out_size, 31337.f);
        return;
    }

    auto WT = [&](const float* s, int K, int N) {
        k_wt<<<dim3(K / 32, N / 32), 256, 0, stream>>>(s, slot, K, N);
    };

    // ---- FF helper: x = 0.5*(silu(ln@Wup+bu)@Wdn + bd) + resid ----
    auto ff_block = [&](const float* lng, const float* lnb, const float* upw, const float* upb,
                        const float* dnw, const float* dnb, const float* resid,
                        const float* xsrc) {
        k_ln<false><<<R_TOT, 256, 0, stream>>>(xsrc, lng, lnb, ln_buf);
        WT(upw, 1024, 4096);
        k_gemm256<1><<<dim3(63, 16), 512, 0, stream>>>(ln_buf, DMODEL, slot, DMODEL, upb, 1.f,
                                                       mid, DFF, nullptr, R_TOT, DFF, DMODEL);
        WT(dnw, 4096, 1024);
        k_gemm256<2><<<dim3(63, 4), 512, 0, stream>>>(mid, DFF, slot, DFF, dnb, 0.5f, xs, DMODEL,
                                                      resid, R_TOT, DMODEL, DFF);
    };

    // ---- FF1 ----
    ff_block(ff1_ln_g, ff1_ln_b, ff1_up_w, ff1_up_b, ff1_down_w, ff1_down_b, x_in, x_in);

    // ---- Attention ----
    k_ln<false><<<R_TOT, 256, 0, stream>>>(xs, attn_ln_g, attn_ln_b, ln_buf);
    k_rel<<<CTX * CTX, 128, 0, stream>>>(rel_emb, dists, rel_bf);
    WT(wq, 1024, 1024);
    k_gemm256<0><<<dim3(63, 4), 512, 0, stream>>>(ln_buf, DMODEL, slot, DMODEL, nullptr, SCALE_Q,
                                                  bufB, DMODEL, nullptr, R_TOT, DMODEL, DMODEL);
    WT(wkv, 1024, 2048);
    for (int h = 0; h < 2; ++h) {
        const int bn0 = h * ABN, m0 = bn0 * 8;
        const u16* lnc = ln_buf + (size_t)bn0 * CTX * DMODEL;
        k_gemm256<0><<<dim3(32, 8), 512, 0, stream>>>(lnc, DMODEL, slot, DMODEL, nullptr, 1.f,
                                                      bufA, 2 * DMODEL, nullptr, AROWS,
                                                      2 * DMODEL, DMODEL);
        k_vt<<<dim3(AM, 4), 256, 0, stream>>>(bufA, vT);
        k_qk<<<dim3(2, 2, AM), 256, 0, stream>>>(bufB, bufA, smid, bn0);
        k_pos<<<dim3(3, 2, CTX), 256, 0, stream>>>(bufB, rel_bf, smid, m0);
        k_softmax<<<AM * CTX, 256, 0, stream>>>(smid);
        k_pv<<<dim3(2, 1, AM), 256, 0, stream>>>(smid, vT, bufB, bn0);
    }
    WT(wo, 1024, 1024);
    k_gemm256<2><<<dim3(63, 4), 512, 0, stream>>>(bufB, DMODEL, slot, DMODEL, wo_b, 1.f, xs,
                                                  DMODEL, xs, R_TOT, DMODEL, DMODEL);

    // ---- Conv module: up (a|gate) -> GLU in-place -> dwconv a->gate region -> down ----
    k_ln<false><<<R_TOT, 256, 0, stream>>>(xs, conv_ln_g, conv_ln_b, ln_buf);
    WT(conv_up_w, 1024, 4096);
    k_gemm256<0><<<dim3(63, 16), 512, 0, stream>>>(ln_buf, DMODEL, slot, DMODEL, conv_up_b, 1.f,
                                                   mid, DFF, nullptr, R_TOT, DFF, DMODEL);
    k_glu<<<R_TOT, 256, 0, stream>>>(mid);
    k_dwconv<<<dim3(125, 8, 8), 256, 0, stream>>>(mid, dw_w, bn_g, bn_b, bn_mean, bn_var,
                                                  mid + INNER);
    WT(conv_down_w, 2048, 1024);
    k_gemm256<2><<<dim3(63, 4), 512, 0, stream>>>(mid + INNER, DFF, slot, INNER, conv_down_b,
                                                  1.f, xs, DMODEL, xs, R_TOT, DMODEL, INNER);

    // ---- FF2 ----
    ff_block(ff2_ln_g, ff2_ln_b, ff2_up_w, ff2_up_b, ff2_down_w, ff2_down_b, xs, xs);

    // ---- final LayerNorm (in-place on d_out) ----
    k_ln<true><<<R_TOT, 256, 0, stream>>>(xs, post_ln_g, post_ln_b, d_out);
}

// Round 6
// 1956.722 us; speedup vs baseline: 1.2557x; 1.0081x over previous
//
#include <hip/hip_runtime.h>

typedef unsigned short u16;
typedef unsigned int u32;
using short8 = __attribute__((ext_vector_type(8))) short;
using floatx4 = __attribute__((ext_vector_type(4))) float;

#define DMODEL 1024
#define DFF 4096
#define INNER 2048
#define DH 128
#define CTX 200
#define R_TOT 16000
#define ABN 40  // attention bn per chunk (2 chunks)
#define AROWS (ABN * CTX)
#define AM (ABN * 8)
#define SCALE_Q 0.08838834764831845f

__device__ __forceinline__ u16 f2bf(float f) {
    union { float f; u32 u; } v; v.f = f;
    u32 r = v.u + 0x7FFFu + ((v.u >> 16) & 1u);
    return (u16)(r >> 16);
}
__device__ __forceinline__ float bf2f(u16 u) {
    union { u32 u; float f; } v; v.u = ((u32)u) << 16; return v.f;
}
__device__ __forceinline__ float sigmoidf_(float x) { return 1.f / (1.f + __expf(-x)); }

__device__ __forceinline__ void load_lds16(const void* g, void* l) {
    __builtin_amdgcn_global_load_lds((const __attribute__((address_space(1))) u32*)g,
                                     (__attribute__((address_space(3))) u32*)l, 16, 0, 0);
}

// ============== 256x256 tile GEMM: BK=64, 8 waves (2Mx4N), T3 2-phase ==============
template <typename RowMap>
__device__ __forceinline__ void stage256(const char* __restrict__ src, RowMap rowoff, int nrows,
                                         int row0, int k0b, char* dst) {
    const int lane = threadIdx.x & 63;
    const int wave = threadIdx.x >> 6;
#pragma unroll
    for (int r = 0; r < 4; ++r) {
        int o = r * 8192 + wave * 1024 + lane * 16;
        int row = o >> 7;
        int srcb = (o & 127) ^ ((row & 7) << 4);
        int grow = row0 + row;
        grow = (grow < nrows) ? grow : (nrows - 1);
        const char* g = src + rowoff(grow) + k0b + srcb;
        load_lds16(g, dst + r * 8192 + wave * 1024);
    }
}

// T3 recipe: per K-tile { STAGE(nxt) ; ds_read cur ; setprio(1) MFMA setprio(0) ;
//                        lgkmcnt(0)+vmcnt(0) ; one barrier }
template <typename RMA, typename RMB, typename Epi>
__device__ __forceinline__ void gemm256_core(const char* __restrict__ A, RMA rma, int a_rows,
                                             const char* __restrict__ B, RMB rmb, int b_rows,
                                             int K, int row0, int col0, char* lds, Epi epi) {
    const int lane = threadIdx.x & 63;
    const int wave = threadIdx.x >> 6;
    const int wrow = (wave >> 2) * 128;
    const int wcol = (wave & 3) * 64;
    const int lr = lane & 15;
    const int kg = lane >> 4;
    const int nt = K >> 6;

    floatx4 acc[8][4];
#pragma unroll
    for (int i = 0; i < 8; ++i)
#pragma unroll
        for (int j = 0; j < 4; ++j) acc[i][j] = (floatx4){0.f, 0.f, 0.f, 0.f};

    stage256(A, rma, a_rows, row0, 0, lds);
    stage256(B, rmb, b_rows, col0, 0, lds + 32768);
    asm volatile("s_waitcnt vmcnt(0)" ::: "memory");
    __builtin_amdgcn_s_barrier();

    for (int t = 0; t < nt; ++t) {
        char* cur = lds + (t & 1) * 65536;
        char* nxt = lds + ((t + 1) & 1) * 65536;
        if (t + 1 < nt) {
            stage256(A, rma, a_rows, row0, (t + 1) << 7, nxt);
            stage256(B, rmb, b_rows, col0, (t + 1) << 7, nxt + 32768);
        }
#pragma unroll
        for (int ks = 0; ks < 2; ++ks) {
            short8 av[8], bv[4];
#pragma unroll
            for (int mi = 0; mi < 8; ++mi) {
                int row = wrow + mi * 16 + lr;
                int cb = (ks * 64 + kg * 16) ^ ((row & 7) << 4);
                av[mi] = *(const short8*)(cur + row * 128 + cb);
            }
#pragma unroll
            for (int ni = 0; ni < 4; ++ni) {
                int row = wcol + ni * 16 + lr;
                int cb = (ks * 64 + kg * 16) ^ ((row & 7) << 4);
                bv[ni] = *(const short8*)(cur + 32768 + row * 128 + cb);
            }
            __builtin_amdgcn_s_setprio(1);
#pragma unroll
            for (int mi = 0; mi < 8; ++mi)
#pragma unroll
                for (int ni = 0; ni < 4; ++ni)
                    acc[mi][ni] = __builtin_amdgcn_mfma_f32_16x16x32_bf16(av[mi], bv[ni],
                                                                          acc[mi][ni], 0, 0, 0);
            __builtin_amdgcn_s_setprio(0);
        }
        if (t + 1 < nt)
            asm volatile("s_waitcnt vmcnt(0) lgkmcnt(0)" ::: "memory");
        else
            asm volatile("s_waitcnt lgkmcnt(0)" ::: "memory");
        __builtin_amdgcn_sched_barrier(0);
        __builtin_amdgcn_s_barrier();
    }
#pragma unroll
    for (int mi = 0; mi < 8; ++mi)
#pragma unroll
        for (int ni = 0; ni < 4; ++ni)
#pragma unroll
            for (int rr = 0; rr < 4; ++rr)
                epi(row0 + wrow + mi * 16 + kg * 4 + rr, col0 + wcol + ni * 16 + lr,
                    acc[mi][ni][rr]);
}

// XCD stripe-cluster remap: gx MUST be a multiple of 8. XCD x owns bx-stripe
// [x*gxs, (x+1)*gxs), all by; within XCD blocks walk column-major so the ~32
// concurrent blocks form a gxs x (32/gxs) cluster sharing A- and B-panels, and the
// XCD's whole A-stripe (gxs*256 rows) stays L2-resident across by passes. Bijective.
__device__ __forceinline__ void xcd_stripe_remap(int& bx, int& by) {
    const int gx = gridDim.x;
    const int gxs = gx >> 3;
    const int id = blockIdx.y * gx + blockIdx.x;
    const int xcd = id & 7;
    const int local = id >> 3;
    bx = xcd * gxs + (local % gxs);
    by = local / gxs;
}

// MODE 0: bf16 out = alpha*v + bias ; MODE 1: bf16 out = silu(v+bias) ;
// MODE 2: f32 out = alpha*(v+bias) + resid
template <int MODE>
__global__ __launch_bounds__(512, 2) void k_gemm256(const u16* __restrict__ A, int lda,
                                                    const u16* __restrict__ Bt, int ldb,
                                                    const float* __restrict__ bias, float alpha,
                                                    void* out, int ldc, const float* resid,
                                                    int M, int N, int K) {
    __shared__ __align__(128) char lds[131072];
    int bx, by;
    xcd_stripe_remap(bx, by);
    const int row0 = bx * 256, col0 = by * 256;
    if (row0 >= M) return;  // pad blocks (gx rounded up to multiple of 8)
    u16* ob = (u16*)out;
    float* of = (float*)out;
    const size_t la = (size_t)lda * 2, lb = (size_t)ldb * 2;
    gemm256_core((const char*)A, [=](int r) { return (size_t)r * la; }, M,
                 (const char*)Bt, [=](int r) { return (size_t)r * lb; }, N, K, row0, col0, lds,
                 [&](int r, int c, float v) {
                     if (r >= M) return;
                     size_t idx = (size_t)r * ldc + c;
                     float bb = bias ? bias[c] : 0.f;
                     if (MODE == 0) {
                         ob[idx] = f2bf(alpha * v + bb);
                     } else if (MODE == 1) {
                         float t = v + bb;
                         ob[idx] = f2bf(t * sigmoidf_(t));
                     } else {
                         of[idx] = alpha * (v + bb) + resid[idx];
                     }
                 });
}

// ============== 128x128 tile core (attention-internal GEMMs), T3 pipeline ==========
template <typename RowMap>
__device__ __forceinline__ void stage_tile_g(const char* __restrict__ src, RowMap rowoff,
                                             int nrows, int row0, int k0b, char* tile) {
    const int lane = threadIdx.x & 63;
    const int wave = threadIdx.x >> 6;
#pragma unroll
    for (int r = 0; r < 4; ++r) {
        int o = r * 4096 + wave * 1024 + lane * 16;
        int row = o >> 7;
        int srcb = (o & 127) ^ ((row & 7) << 4);
        int grow = row0 + row;
        grow = (grow < nrows) ? grow : (nrows - 1);
        const char* g = src + rowoff(grow) + k0b + srcb;
        load_lds16(g, tile + r * 4096 + wave * 1024);
    }
}

template <typename RMA, typename RMB, typename Epi>
__device__ __forceinline__ void gemm_core_g(const char* __restrict__ A, RMA rma, int a_rows,
                                            const char* __restrict__ B, RMB rmb, int b_rows,
                                            int K, int row0, int col0, char* lds, Epi epi) {
    const int lane = threadIdx.x & 63;
    const int wave = threadIdx.x >> 6;
    const int wrow = (wave >> 1) * 64;
    const int wcol = (wave & 1) * 64;
    const int lr = lane & 15;
    const int kg = lane >> 4;
    const int nt = K >> 6;

    floatx4 acc[4][4];
#pragma unroll
    for (int i = 0; i < 4; ++i)
#pragma unroll
        for (int j = 0; j < 4; ++j) acc[i][j] = (floatx4){0.f, 0.f, 0.f, 0.f};

    stage_tile_g(A, rma, a_rows, row0, 0, lds);
    stage_tile_g(B, rmb, b_rows, col0, 0, lds + 16384);
    asm volatile("s_waitcnt vmcnt(0)" ::: "memory");
    __builtin_amdgcn_s_barrier();

    for (int t = 0; t < nt; ++t) {
        char* cur = lds + (t & 1) * 32768;
        char* nxt = lds + ((t + 1) & 1) * 32768;
        if (t + 1 < nt) {
            stage_tile_g(A, rma, a_rows, row0, (t + 1) << 7, nxt);
            stage_tile_g(B, rmb, b_rows, col0, (t + 1) << 7, nxt + 16384);
        }
#pragma unroll
        for (int ks = 0; ks < 2; ++ks) {
            short8 av[4], bv[4];
#pragma unroll
            for (int mi = 0; mi < 4; ++mi) {
                int row = wrow + mi * 16 + lr;
                int cb = (ks * 64 + kg * 16) ^ ((row & 7) << 4);
                av[mi] = *(const short8*)(cur + row * 128 + cb);
            }
#pragma unroll
            for (int ni = 0; ni < 4; ++ni) {
                int row = wcol + ni * 16 + lr;
                int cb = (ks * 64 + kg * 16) ^ ((row & 7) << 4);
                bv[ni] = *(const short8*)(cur + 16384 + row * 128 + cb);
            }
            __builtin_amdgcn_s_setprio(1);
#pragma unroll
            for (int mi = 0; mi < 4; ++mi)
#pragma unroll
                for (int ni = 0; ni < 4; ++ni)
                    acc[mi][ni] = __builtin_amdgcn_mfma_f32_16x16x32_bf16(av[mi], bv[ni],
                                                                          acc[mi][ni], 0, 0, 0);
            __builtin_amdgcn_s_setprio(0);
        }
        if (t + 1 < nt)
            asm volatile("s_waitcnt vmcnt(0) lgkmcnt(0)" ::: "memory");
        else
            asm volatile("s_waitcnt lgkmcnt(0)" ::: "memory");
        __builtin_amdgcn_sched_barrier(0);
        __builtin_amdgcn_s_barrier();
    }
#pragma unroll
    for (int mi = 0; mi < 4; ++mi)
#pragma unroll
        for (int ni = 0; ni < 4; ++ni)
#pragma unroll
            for (int rr = 0; rr < 4; ++rr)
                epi(row0 + wrow + mi * 16 + kg * 4 + rr, col0 + wcol + ni * 16 + lr,
                    acc[mi][ni][rr]);
}

// scores[z][i][j] = q_scaled[i].k[j]  (bf16, cols padded to 256), z = local bnh
__global__ __launch_bounds__(256, 2) void k_qk(const u16* __restrict__ q,
                                               const u16* __restrict__ kvc,
                                               u16* __restrict__ sc, int bn0) {
    __shared__ __align__(128) char lds[65536];
    const int z = blockIdx.z, bnl = z >> 3, h = z & 7;
    const char* A = (const char*)(q + ((size_t)(bn0 + bnl) * CTX) * DMODEL + h * DH);
    const char* B = (const char*)(kvc + ((size_t)bnl * CTX) * (2 * DMODEL) + h * DH);
    u16* out = sc + (size_t)z * CTX * 256;
    gemm_core_g(A, [](int r) { return (size_t)r * (DMODEL * 2); }, CTX, B,
                [](int r) { return (size_t)r * (4 * DMODEL); }, CTX, DH, blockIdx.x * 128,
                blockIdx.y * 128, lds, [&](int r, int c, float v) {
                    if (r < CTX) out[(size_t)r * 256 + c] = f2bf(v);
                });
}

// scores[m][i][j] += q'[m].rel[i][j]  (batched over i; A gathered from q via row map)
__global__ __launch_bounds__(256, 2) void k_pos(const u16* __restrict__ q,
                                                const u16* __restrict__ rel,
                                                u16* __restrict__ sc, int m0) {
    __shared__ __align__(128) char lds[65536];
    const int i = blockIdx.z;
    const char* B = (const char*)(rel + (size_t)i * CTX * DH);
    u16* out = sc + i * 256;
    gemm_core_g((const char*)q,
                [=](int r) {
                    int m = m0 + r;
                    return (size_t)(((m >> 3) * CTX + i) * DMODEL + (m & 7) * DH) * 2;
                },
                AM, B, [](int r) { return (size_t)r * (DH * 2); }, CTX, DH, blockIdx.x * 128,
                blockIdx.y * 128, lds, [&](int r, int c, float v) {
                    if (r < AM) {
                        size_t idx = (size_t)r * (CTX * 256) + c;
                        out[idx] = f2bf(bf2f(out[idx]) + v);
                    }
                });
}

// attn_out[(bn0+z/8)*CTX+i][(z&7)*DH+dh] = P[z][i][:].vT[z][dh][:]  (K=256 padded)
__global__ __launch_bounds__(256, 2) void k_pv(const u16* __restrict__ P,
                                               const u16* __restrict__ vT,
                                               u16* __restrict__ attn, int bn0) {
    __shared__ __align__(128) char lds[65536];
    const int z = blockIdx.z;
    u16* out = attn + ((size_t)(bn0 + (z >> 3)) * CTX) * DMODEL + (z & 7) * DH;
    const char* A = (const char*)(P + (size_t)z * CTX * 256);
    const char* B = (const char*)(vT + (size_t)z * DH * 256);
    gemm_core_g(A, [](int r) { return (size_t)r * 512; }, CTX, B,
                [](int r) { return (size_t)r * 512; }, DH, 256, blockIdx.x * 128, 0, lds,
                [&](int r, int c, float v) {
                    if (r < CTX) out[(size_t)r * DMODEL + c] = f2bf(v);
                });
}

// ---------------- LayerNorm ----------------
template <bool OUTF32>
__global__ __launch_bounds__(256) void k_ln(const float* __restrict__ x,
                                            const float* __restrict__ g,
                                            const float* __restrict__ b, void* __restrict__ out) {
    const int row = blockIdx.x, t = threadIdx.x, lane = t & 63, wv = t >> 6;
    const float4 v = ((const float4*)(x + (size_t)row * DMODEL))[t];
    float s = v.x + v.y + v.z + v.w;
    float q = v.x * v.x + v.y * v.y + v.z * v.z + v.w * v.w;
#pragma unroll
    for (int off = 32; off > 0; off >>= 1) { s += __shfl_down(s, off); q += __shfl_down(q, off); }
    __shared__ float rs_[4], rq_[4];
    if (lane == 0) { rs_[wv] = s; rq_[wv] = q; }
    __syncthreads();
    s = rs_[0] + rs_[1] + rs_[2] + rs_[3];
    q = rq_[0] + rq_[1] + rq_[2] + rq_[3];
    const float mu = s * (1.f / DMODEL);
    const float rstd = rsqrtf(q * (1.f / DMODEL) - mu * mu + 1e-5f);
    const float4 gv = ((const float4*)g)[t];
    const float4 bv = ((const float4*)b)[t];
    float o0 = (v.x - mu) * rstd * gv.x + bv.x;
    float o1 = (v.y - mu) * rstd * gv.y + bv.y;
    float o2 = (v.z - mu) * rstd * gv.z + bv.z;
    float o3 = (v.w - mu) * rstd * gv.w + bv.w;
    if (OUTF32) {
        ((float4*)out)[(size_t)row * 256 + t] = make_float4(o0, o1, o2, o3);
    } else {
        ushort4 r4;
        r4.x = f2bf(o0); r4.y = f2bf(o1); r4.z = f2bf(o2); r4.w = f2bf(o3);
        ((ushort4*)out)[(size_t)row * 256 + t] = r4;
    }
}

// softmax over j, in-place on bf16 scores; zeroes pad cols [CTX,256)
__global__ __launch_bounds__(256) void k_softmax(u16* __restrict__ sc) {
    const size_t row = blockIdx.x;
    const int t = threadIdx.x, lane = t & 63, wv = t >> 6;
    float v = (t < CTX) ? bf2f(sc[row * 256 + t]) : -3.0e38f;
    float m = v;
#pragma unroll
    for (int off = 32; off > 0; off >>= 1) m = fmaxf(m, __shfl_down(m, off));
    __shared__ float rm[4], rsum[4];
    if (lane == 0) rm[wv] = m;
    __syncthreads();
    m = fmaxf(fmaxf(rm[0], rm[1]), fmaxf(rm[2], rm[3]));
    float e = (t < CTX) ? __expf(v - m) : 0.f;
    float s = e;
#pragma unroll
    for (int off = 32; off > 0; off >>= 1) s += __shfl_down(s, off);
    if (lane == 0) rsum[wv] = s;
    __syncthreads();
    s = rsum[0] + rsum[1] + rsum[2] + rsum[3];
    sc[row * 256 + t] = f2bf(e / s);
}

// GLU over mid[16000][4096]: a = cols [0,2048), gate = cols [2048,4096); in-place on a
__global__ __launch_bounds__(256) void k_glu(u16* __restrict__ mid) {
    const size_t r = blockIdx.x;
    const int c = threadIdx.x * 8;
    const short8 a8 = *(const short8*)(mid + r * 4096 + c);
    const short8 g8 = *(const short8*)(mid + r * 4096 + 2048 + c);
    short8 o8;
#pragma unroll
    for (int e = 0; e < 8; ++e) {
        float av = bf2f((u16)a8[e]), gg = bf2f((u16)g8[e]);
        o8[e] = (short)f2bf(av * sigmoidf_(gg));
    }
    *(short8*)(mid + r * 4096 + c) = o8;
}

// depthwise conv(K=15,pad=7)+BN(eval)+silu ; in = a-region (ld 4096), out = gate-region
__global__ __launch_bounds__(256) void k_dwconv(const u16* __restrict__ in,
                                                const float* __restrict__ w,
                                                const float* __restrict__ bng,
                                                const float* __restrict__ bnb,
                                                const float* __restrict__ bnm,
                                                const float* __restrict__ bnv,
                                                u16* __restrict__ out) {
    const int b = blockIdx.z, lt = blockIdx.x, cg = blockIdx.y;
    const int c = cg * 256 + threadIdx.x;  // 0..2047
    const int l0 = lt * 16;
    __shared__ u16 s[30][256];
#pragma unroll
    for (int rr = 0; rr < 30; ++rr) {
        int l = l0 + rr - 7;
        u16 v = 0;
        if (l >= 0 && l < 2000) v = in[((size_t)b * 2000 + l) * 4096 + c];
        s[rr][threadIdx.x] = v;
    }
    __syncthreads();
    float wv[15];
#pragma unroll
    for (int k = 0; k < 15; ++k) wv[k] = w[c * 15 + k];
    const float sc = rsqrtf(bnv[c] + 1e-5f) * bng[c];
    const float mean = bnm[c], bb = bnb[c];
#pragma unroll
    for (int l = 0; l < 16; ++l) {
        float acc = 0.f;
#pragma unroll
        for (int k = 0; k < 15; ++k) acc += bf2f(s[l + k][threadIdx.x]) * wv[k];
        float h = (acc - mean) * sc + bb;
        h = h * sigmoidf_(h);
        out[((size_t)b * 2000 + l0 + l) * 4096 + c] = f2bf(h);
    }
}

// weight transpose f32[K,N] -> bf16[N,K]
__global__ __launch_bounds__(256) void k_wt(const float* __restrict__ w, u16* __restrict__ wt,
                                            int K, int N) {
    __shared__ float tile[32][33];
    const int k0 = blockIdx.x * 32, n0 = blockIdx.y * 32;
    const int tx = threadIdx.x & 31, ty = threadIdx.x >> 5;
#pragma unroll
    for (int i = 0; i < 32; i += 8) tile[ty + i][tx] = w[(size_t)(k0 + ty + i) * N + n0 + tx];
    __syncthreads();
#pragma unroll
    for (int i = 0; i < 32; i += 8)
        wt[(size_t)(n0 + ty + i) * K + k0 + tx] = f2bf(tile[tx][ty + i]);
}

// rel_bf16[i][j][dh] = bf16(rel_emb[dist[i][j]][dh])
__global__ void k_rel(const float* __restrict__ emb, const int* __restrict__ dist,
                      u16* __restrict__ rel) {
    const int bid = blockIdx.x;
    const int d = dist[bid];
    rel[(size_t)bid * DH + threadIdx.x] = f2bf(emb[(size_t)d * DH + threadIdx.x]);
}

// vT[z][dh][j] = v_chunk[bnl*CTX+j][DMODEL + h*DH + dh], zero-padded j in [CTX,256)
__global__ __launch_bounds__(256) void k_vt(const u16* __restrict__ kvc, u16* __restrict__ vT) {
    __shared__ u16 t_[64 * 130];
    const int z = blockIdx.x, jt = blockIdx.y;
    const int bnl = z >> 3, h = z & 7;
    const int j0 = jt * 64;
    for (int idx = threadIdx.x; idx < 8192; idx += 256) {
        int j = idx >> 7, dh = idx & 127;
        int jj = j0 + j;
        u16 val = 0;
        if (jj < CTX) val = kvc[((size_t)(bnl * CTX + jj)) * (2 * DMODEL) + DMODEL + h * DH + dh];
        t_[j * 130 + dh] = val;
    }
    __syncthreads();
    for (int idx = threadIdx.x; idx < 8192; idx += 256) {
        int dh = idx >> 6, j = idx & 63;
        vT[((size_t)z * DH + dh) * 256 + j0 + j] = t_[j * 130 + dh];
    }
}

__global__ void k_fill(float* o, int n, float v) {
    int i = blockIdx.x * 256 + threadIdx.x;
    if (i < n) o[i] = v;
}

extern "C" void kernel_launch(void* const* d_in, const int* in_sizes, int n_in, void* d_out,
                              int out_size, void* d_ws, size_t ws_size, hipStream_t stream) {
    const float* x_in = (const float*)d_in[0];
    const int* dists = (const int*)d_in[1];
    const float* ff1_ln_g = (const float*)d_in[2];
    const float* ff1_ln_b = (const float*)d_in[3];
    const float* ff1_up_w = (const float*)d_in[4];
    const float* ff1_up_b = (const float*)d_in[5];
    const float* ff1_down_w = (const float*)d_in[6];
    const float* ff1_down_b = (const float*)d_in[7];
    const float* attn_ln_g = (const float*)d_in[8];
    const float* attn_ln_b = (const float*)d_in[9];
    const float* wq = (const float*)d_in[10];
    const float* wkv = (const float*)d_in[11];
    const float* wo = (const float*)d_in[12];
    const float* wo_b = (const float*)d_in[13];
    const float* rel_emb = (const float*)d_in[14];
    const float* conv_ln_g = (const float*)d_in[15];
    const float* conv_ln_b = (const float*)d_in[16];
    const float* conv_up_w = (const float*)d_in[17];
    const float* conv_up_b = (const float*)d_in[18];
    const float* dw_w = (const float*)d_in[19];
    const float* bn_g = (const float*)d_in[20];
    const float* bn_b = (const float*)d_in[21];
    const float* bn_mean = (const float*)d_in[22];
    const float* bn_var = (const float*)d_in[23];
    const float* conv_down_w = (const float*)d_in[24];
    const float* conv_down_b = (const float*)d_in[25];
    const float* ff2_ln_g = (const float*)d_in[26];
    const float* ff2_ln_b = (const float*)d_in[27];
    const float* ff2_up_w = (const float*)d_in[28];
    const float* ff2_up_b = (const float*)d_in[29];
    const float* ff2_down_w = (const float*)d_in[30];
    const float* ff2_down_b = (const float*)d_in[31];
    const float* post_ln_g = (const float*)d_in[32];
    const float* post_ln_b = (const float*)d_in[33];

    char* W = (char*)d_ws;
    size_t off = 0;
    auto alloc = [&](size_t bytes) {
        char* p = W + off;
        off += (bytes + 255) & ~(size_t)255;
        return (u16*)p;
    };
    u16* slot = alloc((size_t)4096 * 1024 * 2);              // 8.4 MB
    u16* ln_buf = alloc((size_t)R_TOT * DMODEL * 2);         // 32.8 MB
    u16* arena = alloc((size_t)R_TOT * DFF * 2);             // 131.1 MB
    u16* mid = arena;
    u16* rel_bf = arena;                                     // 10.24 MB
    u16* bufA = rel_bf + (size_t)CTX * CTX * DH;             // kv chunk, 32.8 MB
    u16* bufB = bufA + (size_t)AROWS * 2 * DMODEL;           // q / attn_out, 32.8 MB
    u16* smid = bufB + (size_t)R_TOT * DMODEL;               // scores, 32.8 MB
    u16* vT = smid + (size_t)AM * CTX * 256;                 // 21.0 MB
    float* xs = (float*)d_out;                               // f32 residual stream in d_out

    if (ws_size < off) {  // sentinel: absmax ~= 31337 means ws too small
        k_fill<<<(out_size + 255) / 256, 256, 0, stream>>>((float*)d_out, out_size, 31337.f);
        return;
    }

    auto WT = [&](const float* s, int K, int N) {
        k_wt<<<dim3(K / 32, N / 32), 256, 0, stream>>>(s, slot, K, N);
    };

    // grids: gx padded to multiple of 8 (pad blocks early-exit on row0 >= M)
    const dim3 gUP(64, 16);   // M=16000, N=4096
    const dim3 gSQ(64, 4);    // M=16000, N=1024
    const dim3 gKV(32, 8);    // M=8000,  N=2048

    // ---- FF helper: x = 0.5*(silu(ln@Wup+bu)@Wdn + bd) + resid ----
    auto ff_block = [&](const float* lng, const float* lnb, const float* upw, const float* upb,
                        const float* dnw, const float* dnb, const float* resid,
                        const float* xsrc) {
        k_ln<false><<<R_TOT, 256, 0, stream>>>(xsrc, lng, lnb, ln_buf);
        WT(upw, 1024, 4096);
        k_gemm256<1><<<gUP, 512, 0, stream>>>(ln_buf, DMODEL, slot, DMODEL, upb, 1.f, mid, DFF,
                                              nullptr, R_TOT, DFF, DMODEL);
        WT(dnw, 4096, 1024);
        k_gemm256<2><<<gSQ, 512, 0, stream>>>(mid, DFF, slot, DFF, dnb, 0.5f, xs, DMODEL, resid,
                                              R_TOT, DMODEL, DFF);
    };

    // ---- FF1 ----
    ff_block(ff1_ln_g, ff1_ln_b, ff1_up_w, ff1_up_b, ff1_down_w, ff1_down_b, x_in, x_in);

    // ---- Attention ----
    k_ln<false><<<R_TOT, 256, 0, stream>>>(xs, attn_ln_g, attn_ln_b, ln_buf);
    k_rel<<<CTX * CTX, 128, 0, stream>>>(rel_emb, dists, rel_bf);
    WT(wq, 1024, 1024);
    k_gemm256<0><<<gSQ, 512, 0, stream>>>(ln_buf, DMODEL, slot, DMODEL, nullptr, SCALE_Q, bufB,
                                          DMODEL, nullptr, R_TOT, DMODEL, DMODEL);
    WT(wkv, 1024, 2048);
    for (int h = 0; h < 2; ++h) {
        const int bn0 = h * ABN, m0 = bn0 * 8;
        const u16* lnc = ln_buf + (size_t)bn0 * CTX * DMODEL;
        k_gemm256<0><<<gKV, 512, 0, stream>>>(lnc, DMODEL, slot, DMODEL, nullptr, 1.f, bufA,
                                              2 * DMODEL, nullptr, AROWS, 2 * DMODEL, DMODEL);
        k_vt<<<dim3(AM, 4), 256, 0, stream>>>(bufA, vT);
        k_qk<<<dim3(2, 2, AM), 256, 0, stream>>>(bufB, bufA, smid, bn0);
        k_pos<<<dim3(3, 2, CTX), 256, 0, stream>>>(bufB, rel_bf, smid, m0);
        k_softmax<<<AM * CTX, 256, 0, stream>>>(smid);
        k_pv<<<dim3(2, 1, AM), 256, 0, stream>>>(smid, vT, bufB, bn0);
    }
    WT(wo, 1024, 1024);
    k_gemm256<2><<<gSQ, 512, 0, stream>>>(bufB, DMODEL, slot, DMODEL, wo_b, 1.f, xs, DMODEL, xs,
                                          R_TOT, DMODEL, DMODEL);

    // ---- Conv module: up (a|gate) -> GLU in-place -> dwconv a->gate region -> down ----
    k_ln<false><<<R_TOT, 256, 0, stream>>>(xs, conv_ln_g, conv_ln_b, ln_buf);
    WT(conv_up_w, 1024, 4096);
    k_gemm256<0><<<gUP, 512, 0, stream>>>(ln_buf, DMODEL, slot, DMODEL, conv_up_b, 1.f, mid, DFF,
                                          nullptr, R_TOT, DFF, DMODEL);
    k_glu<<<R_TOT, 256, 0, stream>>>(mid);
    k_dwconv<<<dim3(125, 8, 8), 256, 0, stream>>>(mid, dw_w, bn_g, bn_b, bn_mean, bn_var,
                                                  mid + INNER);
    WT(conv_down_w, 2048, 1024);
    k_gemm256<2><<<gSQ, 512, 0, stream>>>(mid + INNER, DFF, slot, INNER, conv_down_b, 1.f, xs,
                                          DMODEL, xs, R_TOT, DMODEL, INNER);

    // ---- FF2 ----
    ff_block(ff2_ln_g, ff2_ln_b, ff2_up_w, ff2_up_b, ff2_down_w, ff2_down_b, xs, xs);

    // ---- final LayerNorm (in-place on d_out) ----
    k_ln<true><<<R_TOT, 256, 0, stream>>>(xs, post_ln_g, post_ln_b, d_out);
}

// Round 7
// 1939.560 us; speedup vs baseline: 1.2668x; 1.0088x over previous
//
#include <hip/hip_runtime.h>

typedef unsigned short u16;
typedef unsigned int u32;
using short8 = __attribute__((ext_vector_type(8))) short;
using floatx4 = __attribute__((ext_vector_type(4))) float;

#define DMODEL 1024
#define DFF 4096
#define INNER 2048
#define DH 128
#define CTX 200
#define R_TOT 16000
#define ABN 40  // attention bn per chunk (2 chunks)
#define AROWS (ABN * CTX)
#define AM (ABN * 8)
#define SCALE_Q 0.08838834764831845f

__device__ __forceinline__ u16 f2bf(float f) {
    union { float f; u32 u; } v; v.f = f;
    u32 r = v.u + 0x7FFFu + ((v.u >> 16) & 1u);
    return (u16)(r >> 16);
}
__device__ __forceinline__ float bf2f(u16 u) {
    union { u32 u; float f; } v; v.u = ((u32)u) << 16; return v.f;
}
__device__ __forceinline__ float sigmoidf_(float x) { return 1.f / (1.f + __expf(-x)); }

__device__ __forceinline__ void load_lds16(const void* g, void* l) {
    __builtin_amdgcn_global_load_lds((const __attribute__((address_space(1))) u32*)g,
                                     (__attribute__((address_space(3))) u32*)l, 16, 0, 0);
}

// ====== 256x256 tile GEMM: BK=64, 8 waves (2Mx4N), phase-pipelined counted-vmcnt ======
// Stage one HALF (128 rows x 64 k = 16 KB) of a tile slab; XOR swizzle ((row&7)<<4)
// pre-applied on the per-lane GLOBAL source address (LDS dst linear). 2 loads/thread.
template <typename RowMap>
__device__ __forceinline__ void stage_half(const char* __restrict__ src, RowMap rowoff,
                                           int nrows, int row0, int k0b, char* slab, int half) {
    const int lane = threadIdx.x & 63;
    const int wave = threadIdx.x >> 6;
#pragma unroll
    for (int r = 2 * half; r < 2 * half + 2; ++r) {
        int o = r * 8192 + wave * 1024 + lane * 16;
        int row = o >> 7;
        int srcb = (o & 127) ^ ((row & 7) << 4);
        int grow = row0 + row;
        grow = (grow < nrows) ? grow : (nrows - 1);
        load_lds16(src + rowoff(grow) + k0b + srcb, slab + r * 8192 + wave * 1024);
    }
}

// LDS: A dbuf 2x32KB at [0,64K), B tbuf 3x32KB at [64K,160K). Per K-tile, 4 phases:
//   { av ds_read subtile ; stage 1 half ; lgkmcnt(0) ; setprio(1) 16 MFMA setprio(0) ; bar }
// bv read once (phase 0) into regs. Stage slots: q0/q1 -> A(t+1), q2/q3 -> B(t+2).
// Uniform issue order => vmcnt(4) once per tile (q0) proves all halves needed this tile
// have landed while the 2 newest halves stay in flight (loads span 4 phases of compute).
template <typename RMA, typename RMB, typename Epi>
__device__ __forceinline__ void gemm256_core(const char* __restrict__ A, RMA rma, int a_rows,
                                             const char* __restrict__ B, RMB rmb, int b_rows,
                                             int K, int row0, int col0, char* lds, Epi epi) {
    char* ldsA = lds;           // 2 x 32 KB
    char* ldsB = lds + 65536;   // 3 x 32 KB
    const int lane = threadIdx.x & 63;
    const int wave = threadIdx.x >> 6;
    const int wrow = (wave >> 2) * 128;
    const int wcol = (wave & 3) * 64;
    const int lr = lane & 15;
    const int kg = lane >> 4;
    const int nt = K >> 6;

    floatx4 acc[8][4];
#pragma unroll
    for (int i = 0; i < 8; ++i)
#pragma unroll
        for (int j = 0; j < 4; ++j) acc[i][j] = (floatx4){0.f, 0.f, 0.f, 0.f};

    // prologue: FIFO order must match steady-state slot order
    stage_half(B, rmb, b_rows, col0, 0, ldsB, 0);
    stage_half(B, rmb, b_rows, col0, 0, ldsB, 1);
    stage_half(A, rma, a_rows, row0, 0, ldsA, 0);
    stage_half(A, rma, a_rows, row0, 0, ldsA, 1);
    if (nt > 1) {
        stage_half(B, rmb, b_rows, col0, 128, ldsB + 32768, 0);
        stage_half(B, rmb, b_rows, col0, 128, ldsB + 32768, 1);
    }

    int bcur = 0;  // t % 3
    for (int t = 0; t < nt; ++t) {
        char* curA = ldsA + (t & 1) * 32768;
        char* curB = ldsB + bcur * 32768;
        const int bnx2 = (bcur >= 1) ? bcur - 1 : 2;  // (bcur+2)%3
        if (t + 1 < nt)
            asm volatile("s_waitcnt vmcnt(4)" ::: "memory");
        else
            asm volatile("s_waitcnt vmcnt(0)" ::: "memory");
        __builtin_amdgcn_s_barrier();

        short8 bv[4][2];
#pragma unroll
        for (int ni = 0; ni < 4; ++ni) {
            int row = wcol + ni * 16 + lr;
#pragma unroll
            for (int ks = 0; ks < 2; ++ks) {
                int cb = (ks * 64 + kg * 16) ^ ((row & 7) << 4);
                bv[ni][ks] = *(const short8*)(curB + row * 128 + cb);
            }
        }
#pragma unroll
        for (int q = 0; q < 4; ++q) {
            short8 av[2][2];
#pragma unroll
            for (int m2 = 0; m2 < 2; ++m2) {
                int row = wrow + (2 * q + m2) * 16 + lr;
#pragma unroll
                for (int ks = 0; ks < 2; ++ks) {
                    int cb = (ks * 64 + kg * 16) ^ ((row & 7) << 4);
                    av[m2][ks] = *(const short8*)(curA + row * 128 + cb);
                }
            }
            if (q == 0 && t + 1 < nt)
                stage_half(A, rma, a_rows, row0, (t + 1) << 7, ldsA + ((t + 1) & 1) * 32768, 0);
            if (q == 1 && t + 1 < nt)
                stage_half(A, rma, a_rows, row0, (t + 1) << 7, ldsA + ((t + 1) & 1) * 32768, 1);
            if (q == 2 && t + 2 < nt)
                stage_half(B, rmb, b_rows, col0, (t + 2) << 7, ldsB + bnx2 * 32768, 0);
            if (q == 3 && t + 2 < nt)
                stage_half(B, rmb, b_rows, col0, (t + 2) << 7, ldsB + bnx2 * 32768, 1);
            asm volatile("s_waitcnt lgkmcnt(0)" ::: "memory");
            __builtin_amdgcn_sched_barrier(0);
            __builtin_amdgcn_s_setprio(1);
#pragma unroll
            for (int ks = 0; ks < 2; ++ks)
#pragma unroll
                for (int m2 = 0; m2 < 2; ++m2)
#pragma unroll
                    for (int ni = 0; ni < 4; ++ni)
                        acc[2 * q + m2][ni] = __builtin_amdgcn_mfma_f32_16x16x32_bf16(
                            av[m2][ks], bv[ni][ks], acc[2 * q + m2][ni], 0, 0, 0);
            __builtin_amdgcn_s_setprio(0);
            __builtin_amdgcn_s_barrier();
        }
        bcur = (bcur >= 2) ? 0 : bcur + 1;
    }
#pragma unroll
    for (int mi = 0; mi < 8; ++mi)
#pragma unroll
        for (int ni = 0; ni < 4; ++ni)
#pragma unroll
            for (int rr = 0; rr < 4; ++rr)
                epi(row0 + wrow + mi * 16 + kg * 4 + rr, col0 + wcol + ni * 16 + lr,
                    acc[mi][ni][rr]);
}

// XCD stripe-cluster remap: gx MUST be a multiple of 8 (pad blocks early-exit).
__device__ __forceinline__ void xcd_stripe_remap(int& bx, int& by) {
    const int gx = gridDim.x;
    const int gxs = gx >> 3;
    const int id = blockIdx.y * gx + blockIdx.x;
    const int xcd = id & 7;
    const int local = id >> 3;
    bx = xcd * gxs + (local % gxs);
    by = local / gxs;
}

// MODE 0: bf16 out = alpha*v + bias ; MODE 1: bf16 out = silu(v+bias) ;
// MODE 2: f32 out = alpha*(v+bias) + resid
template <int MODE>
__global__ __launch_bounds__(512, 2) void k_gemm256(const u16* __restrict__ A, int lda,
                                                    const u16* __restrict__ Bt, int ldb,
                                                    const float* __restrict__ bias, float alpha,
                                                    void* out, int ldc, const float* resid,
                                                    int M, int N, int K) {
    __shared__ __align__(128) char lds[163840];
    int bx, by;
    xcd_stripe_remap(bx, by);
    const int row0 = bx * 256, col0 = by * 256;
    if (row0 >= M) return;
    u16* ob = (u16*)out;
    float* of = (float*)out;
    const size_t la = (size_t)lda * 2, lb = (size_t)ldb * 2;
    gemm256_core((const char*)A, [=](int r) { return (size_t)r * la; }, M,
                 (const char*)Bt, [=](int r) { return (size_t)r * lb; }, N, K, row0, col0, lds,
                 [&](int r, int c, float v) {
                     if (r >= M) return;
                     size_t idx = (size_t)r * ldc + c;
                     float bb = bias ? bias[c] : 0.f;
                     if (MODE == 0) {
                         ob[idx] = f2bf(alpha * v + bb);
                     } else if (MODE == 1) {
                         float t = v + bb;
                         ob[idx] = f2bf(t * sigmoidf_(t));
                     } else {
                         of[idx] = alpha * (v + bb) + resid[idx];
                     }
                 });
}

// ============== 128x128 tile core (attention-internal GEMMs), T3 2-phase ==========
template <typename RowMap>
__device__ __forceinline__ void stage_tile_g(const char* __restrict__ src, RowMap rowoff,
                                             int nrows, int row0, int k0b, char* tile) {
    const int lane = threadIdx.x & 63;
    const int wave = threadIdx.x >> 6;
#pragma unroll
    for (int r = 0; r < 4; ++r) {
        int o = r * 4096 + wave * 1024 + lane * 16;
        int row = o >> 7;
        int srcb = (o & 127) ^ ((row & 7) << 4);
        int grow = row0 + row;
        grow = (grow < nrows) ? grow : (nrows - 1);
        const char* g = src + rowoff(grow) + k0b + srcb;
        load_lds16(g, tile + r * 4096 + wave * 1024);
    }
}

template <typename RMA, typename RMB, typename Epi>
__device__ __forceinline__ void gemm_core_g(const char* __restrict__ A, RMA rma, int a_rows,
                                            const char* __restrict__ B, RMB rmb, int b_rows,
                                            int K, int row0, int col0, char* lds, Epi epi) {
    const int lane = threadIdx.x & 63;
    const int wave = threadIdx.x >> 6;
    const int wrow = (wave >> 1) * 64;
    const int wcol = (wave & 1) * 64;
    const int lr = lane & 15;
    const int kg = lane >> 4;
    const int nt = K >> 6;

    floatx4 acc[4][4];
#pragma unroll
    for (int i = 0; i < 4; ++i)
#pragma unroll
        for (int j = 0; j < 4; ++j) acc[i][j] = (floatx4){0.f, 0.f, 0.f, 0.f};

    stage_tile_g(A, rma, a_rows, row0, 0, lds);
    stage_tile_g(B, rmb, b_rows, col0, 0, lds + 16384);
    asm volatile("s_waitcnt vmcnt(0)" ::: "memory");
    __builtin_amdgcn_s_barrier();

    for (int t = 0; t < nt; ++t) {
        char* cur = lds + (t & 1) * 32768;
        char* nxt = lds + ((t + 1) & 1) * 32768;
        if (t + 1 < nt) {
            stage_tile_g(A, rma, a_rows, row0, (t + 1) << 7, nxt);
            stage_tile_g(B, rmb, b_rows, col0, (t + 1) << 7, nxt + 16384);
        }
#pragma unroll
        for (int ks = 0; ks < 2; ++ks) {
            short8 av[4], bv[4];
#pragma unroll
            for (int mi = 0; mi < 4; ++mi) {
                int row = wrow + mi * 16 + lr;
                int cb = (ks * 64 + kg * 16) ^ ((row & 7) << 4);
                av[mi] = *(const short8*)(cur + row * 128 + cb);
            }
#pragma unroll
            for (int ni = 0; ni < 4; ++ni) {
                int row = wcol + ni * 16 + lr;
                int cb = (ks * 64 + kg * 16) ^ ((row & 7) << 4);
                bv[ni] = *(const short8*)(cur + 16384 + row * 128 + cb);
            }
            __builtin_amdgcn_s_setprio(1);
#pragma unroll
            for (int mi = 0; mi < 4; ++mi)
#pragma unroll
                for (int ni = 0; ni < 4; ++ni)
                    acc[mi][ni] = __builtin_amdgcn_mfma_f32_16x16x32_bf16(av[mi], bv[ni],
                                                                          acc[mi][ni], 0, 0, 0);
            __builtin_amdgcn_s_setprio(0);
        }
        if (t + 1 < nt)
            asm volatile("s_waitcnt vmcnt(0) lgkmcnt(0)" ::: "memory");
        else
            asm volatile("s_waitcnt lgkmcnt(0)" ::: "memory");
        __builtin_amdgcn_sched_barrier(0);
        __builtin_amdgcn_s_barrier();
    }
#pragma unroll
    for (int mi = 0; mi < 4; ++mi)
#pragma unroll
        for (int ni = 0; ni < 4; ++ni)
#pragma unroll
            for (int rr = 0; rr < 4; ++rr)
                epi(row0 + wrow + mi * 16 + kg * 4 + rr, col0 + wcol + ni * 16 + lr,
                    acc[mi][ni][rr]);
}

// scores[z][i][j] = q_scaled[i].k[j]  (bf16, cols padded to 256), z = local bnh
__global__ __launch_bounds__(256, 2) void k_qk(const u16* __restrict__ q,
                                               const u16* __restrict__ kvc,
                                               u16* __restrict__ sc, int bn0) {
    __shared__ __align__(128) char lds[65536];
    const int z = blockIdx.z, bnl = z >> 3, h = z & 7;
    const char* A = (const char*)(q + ((size_t)(bn0 + bnl) * CTX) * DMODEL + h * DH);
    const char* B = (const char*)(kvc + ((size_t)bnl * CTX) * (2 * DMODEL) + h * DH);
    u16* out = sc + (size_t)z * CTX * 256;
    gemm_core_g(A, [](int r) { return (size_t)r * (DMODEL * 2); }, CTX, B,
                [](int r) { return (size_t)r * (4 * DMODEL); }, CTX, DH, blockIdx.x * 128,
                blockIdx.y * 128, lds, [&](int r, int c, float v) {
                    if (r < CTX) out[(size_t)r * 256 + c] = f2bf(v);
                });
}

// scores[m][i][j] += q'[m].rel[i][j]  (batched over i; A gathered from q via row map)
__global__ __launch_bounds__(256, 2) void k_pos(const u16* __restrict__ q,
                                                const u16* __restrict__ rel,
                                                u16* __restrict__ sc, int m0) {
    __shared__ __align__(128) char lds[65536];
    const int i = blockIdx.z;
    const char* B = (const char*)(rel + (size_t)i * CTX * DH);
    u16* out = sc + i * 256;
    gemm_core_g((const char*)q,
                [=](int r) {
                    int m = m0 + r;
                    return (size_t)(((m >> 3) * CTX + i) * DMODEL + (m & 7) * DH) * 2;
                },
                AM, B, [](int r) { return (size_t)r * (DH * 2); }, CTX, DH, blockIdx.x * 128,
                blockIdx.y * 128, lds, [&](int r, int c, float v) {
                    if (r < AM) {
                        size_t idx = (size_t)r * (CTX * 256) + c;
                        out[idx] = f2bf(bf2f(out[idx]) + v);
                    }
                });
}

// attn_out[(bn0+z/8)*CTX+i][(z&7)*DH+dh] = P[z][i][:].vT[z][dh][:]  (K=256 padded)
__global__ __launch_bounds__(256, 2) void k_pv(const u16* __restrict__ P,
                                               const u16* __restrict__ vT,
                                               u16* __restrict__ attn, int bn0) {
    __shared__ __align__(128) char lds[65536];
    const int z = blockIdx.z;
    u16* out = attn + ((size_t)(bn0 + (z >> 3)) * CTX) * DMODEL + (z & 7) * DH;
    const char* A = (const char*)(P + (size_t)z * CTX * 256);
    const char* B = (const char*)(vT + (size_t)z * DH * 256);
    gemm_core_g(A, [](int r) { return (size_t)r * 512; }, CTX, B,
                [](int r) { return (size_t)r * 512; }, DH, 256, blockIdx.x * 128, 0, lds,
                [&](int r, int c, float v) {
                    if (r < CTX) out[(size_t)r * DMODEL + c] = f2bf(v);
                });
}

// ---------------- LayerNorm ----------------
template <bool OUTF32>
__global__ __launch_bounds__(256) void k_ln(const float* __restrict__ x,
                                            const float* __restrict__ g,
                                            const float* __restrict__ b, void* __restrict__ out) {
    const int row = blockIdx.x, t = threadIdx.x, lane = t & 63, wv = t >> 6;
    const float4 v = ((const float4*)(x + (size_t)row * DMODEL))[t];
    float s = v.x + v.y + v.z + v.w;
    float q = v.x * v.x + v.y * v.y + v.z * v.z + v.w * v.w;
#pragma unroll
    for (int off = 32; off > 0; off >>= 1) { s += __shfl_down(s, off); q += __shfl_down(q, off); }
    __shared__ float rs_[4], rq_[4];
    if (lane == 0) { rs_[wv] = s; rq_[wv] = q; }
    __syncthreads();
    s = rs_[0] + rs_[1] + rs_[2] + rs_[3];
    q = rq_[0] + rq_[1] + rq_[2] + rq_[3];
    const float mu = s * (1.f / DMODEL);
    const float rstd = rsqrtf(q * (1.f / DMODEL) - mu * mu + 1e-5f);
    const float4 gv = ((const float4*)g)[t];
    const float4 bv = ((const float4*)b)[t];
    float o0 = (v.x - mu) * rstd * gv.x + bv.x;
    float o1 = (v.y - mu) * rstd * gv.y + bv.y;
    float o2 = (v.z - mu) * rstd * gv.z + bv.z;
    float o3 = (v.w - mu) * rstd * gv.w + bv.w;
    if (OUTF32) {
        ((float4*)out)[(size_t)row * 256 + t] = make_float4(o0, o1, o2, o3);
    } else {
        ushort4 r4;
        r4.x = f2bf(o0); r4.y = f2bf(o1); r4.z = f2bf(o2); r4.w = f2bf(o3);
        ((ushort4*)out)[(size_t)row * 256 + t] = r4;
    }
}

// softmax over j, in-place on bf16 scores; zeroes pad cols [CTX,256)
__global__ __launch_bounds__(256) void k_softmax(u16* __restrict__ sc) {
    const size_t row = blockIdx.x;
    const int t = threadIdx.x, lane = t & 63, wv = t >> 6;
    float v = (t < CTX) ? bf2f(sc[row * 256 + t]) : -3.0e38f;
    float m = v;
#pragma unroll
    for (int off = 32; off > 0; off >>= 1) m = fmaxf(m, __shfl_down(m, off));
    __shared__ float rm[4], rsum[4];
    if (lane == 0) rm[wv] = m;
    __syncthreads();
    m = fmaxf(fmaxf(rm[0], rm[1]), fmaxf(rm[2], rm[3]));
    float e = (t < CTX) ? __expf(v - m) : 0.f;
    float s = e;
#pragma unroll
    for (int off = 32; off > 0; off >>= 1) s += __shfl_down(s, off);
    if (lane == 0) rsum[wv] = s;
    __syncthreads();
    s = rsum[0] + rsum[1] + rsum[2] + rsum[3];
    sc[row * 256 + t] = f2bf(e / s);
}

// GLU over mid[16000][4096]: a = cols [0,2048), gate = cols [2048,4096); in-place on a
__global__ __launch_bounds__(256) void k_glu(u16* __restrict__ mid) {
    const size_t r = blockIdx.x;
    const int c = threadIdx.x * 8;
    const short8 a8 = *(const short8*)(mid + r * 4096 + c);
    const short8 g8 = *(const short8*)(mid + r * 4096 + 2048 + c);
    short8 o8;
#pragma unroll
    for (int e = 0; e < 8; ++e) {
        float av = bf2f((u16)a8[e]), gg = bf2f((u16)g8[e]);
        o8[e] = (short)f2bf(av * sigmoidf_(gg));
    }
    *(short8*)(mid + r * 4096 + c) = o8;
}

// depthwise conv(K=15,pad=7)+BN(eval)+silu ; in = a-region (ld 4096), out = gate-region
__global__ __launch_bounds__(256) void k_dwconv(const u16* __restrict__ in,
                                                const float* __restrict__ w,
                                                const float* __restrict__ bng,
                                                const float* __restrict__ bnb,
                                                const float* __restrict__ bnm,
                                                const float* __restrict__ bnv,
                                                u16* __restrict__ out) {
    const int b = blockIdx.z, lt = blockIdx.x, cg = blockIdx.y;
    const int c = cg * 256 + threadIdx.x;  // 0..2047
    const int l0 = lt * 16;
    __shared__ u16 s[30][256];
#pragma unroll
    for (int rr = 0; rr < 30; ++rr) {
        int l = l0 + rr - 7;
        u16 v = 0;
        if (l >= 0 && l < 2000) v = in[((size_t)b * 2000 + l) * 4096 + c];
        s[rr][threadIdx.x] = v;
    }
    __syncthreads();
    float wv[15];
#pragma unroll
    for (int k = 0; k < 15; ++k) wv[k] = w[c * 15 + k];
    const float sc = rsqrtf(bnv[c] + 1e-5f) * bng[c];
    const float mean = bnm[c], bb = bnb[c];
#pragma unroll
    for (int l = 0; l < 16; ++l) {
        float acc = 0.f;
#pragma unroll
        for (int k = 0; k < 15; ++k) acc += bf2f(s[l + k][threadIdx.x]) * wv[k];
        float h = (acc - mean) * sc + bb;
        h = h * sigmoidf_(h);
        out[((size_t)b * 2000 + l0 + l) * 4096 + c] = f2bf(h);
    }
}

// weight transpose f32[K,N] -> bf16[N,K]
__global__ __launch_bounds__(256) void k_wt(const float* __restrict__ w, u16* __restrict__ wt,
                                            int K, int N) {
    __shared__ float tile[32][33];
    const int k0 = blockIdx.x * 32, n0 = blockIdx.y * 32;
    const int tx = threadIdx.x & 31, ty = threadIdx.x >> 5;
#pragma unroll
    for (int i = 0; i < 32; i += 8) tile[ty + i][tx] = w[(size_t)(k0 + ty + i) * N + n0 + tx];
    __syncthreads();
#pragma unroll
    for (int i = 0; i < 32; i += 8)
        wt[(size_t)(n0 + ty + i) * K + k0 + tx] = f2bf(tile[tx][ty + i]);
}

// rel_bf16[i][j][dh] = bf16(rel_emb[dist[i][j]][dh])
__global__ void k_rel(const float* __restrict__ emb, const int* __restrict__ dist,
                      u16* __restrict__ rel) {
    const int bid = blockIdx.x;
    const int d = dist[bid];
    rel[(size_t)bid * DH + threadIdx.x] = f2bf(emb[(size_t)d * DH + threadIdx.x]);
}

// vT[z][dh][j] = v_chunk[bnl*CTX+j][DMODEL + h*DH + dh], zero-padded j in [CTX,256)
__global__ __launch_bounds__(256) void k_vt(const u16* __restrict__ kvc, u16* __restrict__ vT) {
    __shared__ u16 t_[64 * 130];
    const int z = blockIdx.x, jt = blockIdx.y;
    const int bnl = z >> 3, h = z & 7;
    const int j0 = jt * 64;
    for (int idx = threadIdx.x; idx < 8192; idx += 256) {
        int j = idx >> 7, dh = idx & 127;
        int jj = j0 + j;
        u16 val = 0;
        if (jj < CTX) val = kvc[((size_t)(bnl * CTX + jj)) * (2 * DMODEL) + DMODEL + h * DH + dh];
        t_[j * 130 + dh] = val;
    }
    __syncthreads();
    for (int idx = threadIdx.x; idx < 8192; idx += 256) {
        int dh = idx >> 6, j = idx & 63;
        vT[((size_t)z * DH + dh) * 256 + j0 + j] = t_[j * 130 + dh];
    }
}

__global__ void k_fill(float* o, int n, float v) {
    int i = blockIdx.x * 256 + threadIdx.x;
    if (i < n) o[i] = v;
}

extern "C" void kernel_launch(void* const* d_in, const int* in_sizes, int n_in, void* d_out,
                              int out_size, void* d_ws, size_t ws_size, hipStream_t stream) {
    const float* x_in = (const float*)d_in[0];
    const int* dists = (const int*)d_in[1];
    const float* ff1_ln_g = (const float*)d_in[2];
    const float* ff1_ln_b = (const float*)d_in[3];
    const float* ff1_up_w = (const float*)d_in[4];
    const float* ff1_up_b = (const float*)d_in[5];
    const float* ff1_down_w = (const float*)d_in[6];
    const float* ff1_down_b = (const float*)d_in[7];
    const float* attn_ln_g = (const float*)d_in[8];
    const float* attn_ln_b = (const float*)d_in[9];
    const float* wq = (const float*)d_in[10];
    const float* wkv = (const float*)d_in[11];
    const float* wo = (const float*)d_in[12];
    const float* wo_b = (const float*)d_in[13];
    const float* rel_emb = (const float*)d_in[14];
    const float* conv_ln_g = (const float*)d_in[15];
    const float* conv_ln_b = (const float*)d_in[16];
    const float* conv_up_w = (const float*)d_in[17];
    const float* conv_up_b = (const float*)d_in[18];
    const float* dw_w = (const float*)d_in[19];
    const float* bn_g = (const float*)d_in[20];
    const float* bn_b = (const float*)d_in[21];
    const float* bn_mean = (const float*)d_in[22];
    const float* bn_var = (const float*)d_in[23];
    const float* conv_down_w = (const float*)d_in[24];
    const float* conv_down_b = (const float*)d_in[25];
    const float* ff2_ln_g = (const float*)d_in[26];
    const float* ff2_ln_b = (const float*)d_in[27];
    const float* ff2_up_w = (const float*)d_in[28];
    const float* ff2_up_b = (const float*)d_in[29];
    const float* ff2_down_w = (const float*)d_in[30];
    const float* ff2_down_b = (const float*)d_in[31];
    const float* post_ln_g = (const float*)d_in[32];
    const float* post_ln_b = (const float*)d_in[33];

    char* W = (char*)d_ws;
    size_t off = 0;
    auto alloc = [&](size_t bytes) {
        char* p = W + off;
        off += (bytes + 255) & ~(size_t)255;
        return (u16*)p;
    };
    u16* slot = alloc((size_t)4096 * 1024 * 2);              // 8.4 MB
    u16* ln_buf = alloc((size_t)R_TOT * DMODEL * 2);         // 32.8 MB
    u16* arena = alloc((size_t)R_TOT * DFF * 2);             // 131.1 MB
    u16* mid = arena;
    u16* rel_bf = arena;                                     // 10.24 MB
    u16* bufA = rel_bf + (size_t)CTX * CTX * DH;             // kv chunk, 32.8 MB
    u16* bufB = bufA + (size_t)AROWS * 2 * DMODEL;           // q / attn_out, 32.8 MB
    u16* smid = bufB + (size_t)R_TOT * DMODEL;               // scores, 32.8 MB
    u16* vT = smid + (size_t)AM * CTX * 256;                 // 21.0 MB
    float* xs = (float*)d_out;                               // f32 residual stream in d_out

    if (ws_size < off) {  // sentinel: absmax ~= 31337 means ws too small
        k_fill<<<(out_size + 255) / 256, 256, 0, stream>>>((float*)d_out, out_size, 31337.f);
        return;
    }

    auto WT = [&](const float* s, int K, int N) {
        k_wt<<<dim3(K / 32, N / 32), 256, 0, stream>>>(s, slot, K, N);
    };

    const dim3 gUP(64, 16);   // M=16000, N=4096
    const dim3 gSQ(64, 4);    // M=16000, N=1024
    const dim3 gKV(32, 8);    // M=8000,  N=2048

    auto ff_block = [&](const float* lng, const float* lnb, const float* upw, const float* upb,
                        const float* dnw, const float* dnb, const float* resid,
                        const float* xsrc) {
        k_ln<false><<<R_TOT, 256, 0, stream>>>(xsrc, lng, lnb, ln_buf);
        WT(upw, 1024, 4096);
        k_gemm256<1><<<gUP, 512, 0, stream>>>(ln_buf, DMODEL, slot, DMODEL, upb, 1.f, mid, DFF,
                                              nullptr, R_TOT, DFF, DMODEL);
        WT(dnw, 4096, 1024);
        k_gemm256<2><<<gSQ, 512, 0, stream>>>(mid, DFF, slot, DFF, dnb, 0.5f, xs, DMODEL, resid,
                                              R_TOT, DMODEL, DFF);
    };

    // ---- FF1 ----
    ff_block(ff1_ln_g, ff1_ln_b, ff1_up_w, ff1_up_b, ff1_down_w, ff1_down_b, x_in, x_in);

    // ---- Attention ----
    k_ln<false><<<R_TOT, 256, 0, stream>>>(xs, attn_ln_g, attn_ln_b, ln_buf);
    k_rel<<<CTX * CTX, 128, 0, stream>>>(rel_emb, dists, rel_bf);
    WT(wq, 1024, 1024);
    k_gemm256<0><<<gSQ, 512, 0, stream>>>(ln_buf, DMODEL, slot, DMODEL, nullptr, SCALE_Q, bufB,
                                          DMODEL, nullptr, R_TOT, DMODEL, DMODEL);
    WT(wkv, 1024, 2048);
    for (int h = 0; h < 2; ++h) {
        const int bn0 = h * ABN, m0 = bn0 * 8;
        const u16* lnc = ln_buf + (size_t)bn0 * CTX * DMODEL;
        k_gemm256<0><<<gKV, 512, 0, stream>>>(lnc, DMODEL, slot, DMODEL, nullptr, 1.f, bufA,
                                              2 * DMODEL, nullptr, AROWS, 2 * DMODEL, DMODEL);
        k_vt<<<dim3(AM, 4), 256, 0, stream>>>(bufA, vT);
        k_qk<<<dim3(2, 2, AM), 256, 0, stream>>>(bufB, bufA, smid, bn0);
        k_pos<<<dim3(3, 2, CTX), 256, 0, stream>>>(bufB, rel_bf, smid, m0);
        k_softmax<<<AM * CTX, 256, 0, stream>>>(smid);
        k_pv<<<dim3(2, 1, AM), 256, 0, stream>>>(smid, vT, bufB, bn0);
    }
    WT(wo, 1024, 1024);
    k_gemm256<2><<<gSQ, 512, 0, stream>>>(bufB, DMODEL, slot, DMODEL, wo_b, 1.f, xs, DMODEL, xs,
                                          R_TOT, DMODEL, DMODEL);

    // ---- Conv module: up (a|gate) -> GLU in-place -> dwconv a->gate region -> down ----
    k_ln<false><<<R_TOT, 256, 0, stream>>>(xs, conv_ln_g, conv_ln_b, ln_buf);
    WT(conv_up_w, 1024, 4096);
    k_gemm256<0><<<gUP, 512, 0, stream>>>(ln_buf, DMODEL, slot, DMODEL, conv_up_b, 1.f, mid, DFF,
                                          nullptr, R_TOT, DFF, DMODEL);
    k_glu<<<R_TOT, 256, 0, stream>>>(mid);
    k_dwconv<<<dim3(125, 8, 8), 256, 0, stream>>>(mid, dw_w, bn_g, bn_b, bn_mean, bn_var,
                                                  mid + INNER);
    WT(conv_down_w, 2048, 1024);
    k_gemm256<2><<<gSQ, 512, 0, stream>>>(mid + INNER, DFF, slot, INNER, conv_down_b, 1.f, xs,
                                          DMODEL, xs, R_TOT, DMODEL, INNER);

    // ---- FF2 ----
    ff_block(ff2_ln_g, ff2_ln_b, ff2_up_w, ff2_up_b, ff2_down_w, ff2_down_b, xs, xs);

    // ---- final LayerNorm (in-place on d_out) ----
    k_ln<true><<<R_TOT, 256, 0, stream>>>(xs, post_ln_g, post_ln_b, d_out);
}